// Round 1
// baseline (11128.756 us; speedup 1.0000x reference)
//
#include <hip/hip_runtime.h>

#define N_NODES 100000
#define E_EDGES 1600000
#define F 256              // feature width at every stage (IN=256, HID=256, mu|lv = 256)
#define LV_OFF 12800000    // 100000*128

// ---------------- degree / normalization ----------------
__global__ void k_init_deg(float* __restrict__ deg) {
    int i = blockIdx.x * 256 + threadIdx.x;
    if (i < N_NODES) deg[i] = 1.0f;   // self-loop
}

__global__ void k_edge_deg(const int* __restrict__ dst, float* __restrict__ deg) {
    int e = blockIdx.x * 256 + threadIdx.x;
    if (e < E_EDGES) atomicAdd(&deg[dst[e]], 1.0f);
}

__global__ void k_dis(float* __restrict__ deg) {
    int i = blockIdx.x * 256 + threadIdx.x;
    if (i < N_NODES) deg[i] = rsqrtf(deg[i]);   // deg >= 1 always
}

// ---------------- build concatenated [W_mu | W_lv] ----------------
__global__ void k_wcat(const float* __restrict__ Wmu, const float* __restrict__ Wlv,
                       float* __restrict__ Wcat) {
    int idx = blockIdx.x * 256 + threadIdx.x;   // 256*256 elements
    int k = idx >> 8, j = idx & 255;
    Wcat[idx] = (j < 128) ? Wmu[k * 128 + j] : Wlv[k * 128 + (j - 128)];
}

// ---------------- fp32 tiled GEMM, epilogue scales by dis[row] ----------------
// C[m, n0+..] = (A[m,:] @ B[:, n]) * dis[m]; optionally duplicated into ACC (self-loop init).
// A: [M,256] row-major, B: [256,256] row-major.
__global__ __launch_bounds__(256) void k_gemm_scaled(
    const float* __restrict__ A, const float* __restrict__ B,
    const float* __restrict__ dis,
    float* __restrict__ G, float* __restrict__ ACC, int M)
{
    __shared__ float As[16][132];   // k-major, padded so float4 reads stay 16B-aligned
    __shared__ float Bs[16][128];

    const int tid = threadIdx.x;
    const int tx = tid & 15, ty = tid >> 4;
    const int m0 = blockIdx.x * 128;
    const int n0 = blockIdx.y * 128;

    float acc[8][8];
#pragma unroll
    for (int i = 0; i < 8; i++)
#pragma unroll
        for (int j = 0; j < 8; j++) acc[i][j] = 0.0f;

    const int arow0 = tid >> 2;   // 0..63
    const int aq    = tid & 3;    // k-quad

    for (int kt = 0; kt < 256; kt += 16) {
        // A tile: 128 rows x 16 k, transposed into As[k][m]
#pragma unroll
        for (int h = 0; h < 2; ++h) {
            int row = arow0 + h * 64;
            int gm = m0 + row; if (gm >= M) gm = M - 1;   // clamp; stores guarded later
            float4 v = *reinterpret_cast<const float4*>(A + (size_t)gm * F + kt + aq * 4);
            As[aq * 4 + 0][row] = v.x;
            As[aq * 4 + 1][row] = v.y;
            As[aq * 4 + 2][row] = v.z;
            As[aq * 4 + 3][row] = v.w;
        }
        // B tile: 16 k-rows x 128 cols
#pragma unroll
        for (int h = 0; h < 2; ++h) {
            int l = tid + h * 256;
            int r = l >> 5, cq = l & 31;
            float4 v = *reinterpret_cast<const float4*>(B + (size_t)(kt + r) * F + n0 + cq * 4);
            *reinterpret_cast<float4*>(&Bs[r][cq * 4]) = v;
        }
        __syncthreads();
#pragma unroll
        for (int k = 0; k < 16; k++) {
            float4 a0 = *reinterpret_cast<const float4*>(&As[k][ty * 8]);
            float4 a1 = *reinterpret_cast<const float4*>(&As[k][ty * 8 + 4]);
            float4 b0 = *reinterpret_cast<const float4*>(&Bs[k][tx * 8]);
            float4 b1 = *reinterpret_cast<const float4*>(&Bs[k][tx * 8 + 4]);
            float av[8] = {a0.x, a0.y, a0.z, a0.w, a1.x, a1.y, a1.z, a1.w};
            float bv[8] = {b0.x, b0.y, b0.z, b0.w, b1.x, b1.y, b1.z, b1.w};
#pragma unroll
            for (int i = 0; i < 8; i++)
#pragma unroll
                for (int j = 0; j < 8; j++)
                    acc[i][j] = fmaf(av[i], bv[j], acc[i][j]);
        }
        __syncthreads();
    }

#pragma unroll
    for (int i = 0; i < 8; i++) {
        int m = m0 + ty * 8 + i;
        if (m >= M) continue;
        float s = dis[m];
        float4 o0 = make_float4(acc[i][0] * s, acc[i][1] * s, acc[i][2] * s, acc[i][3] * s);
        float4 o1 = make_float4(acc[i][4] * s, acc[i][5] * s, acc[i][6] * s, acc[i][7] * s);
        size_t base = (size_t)m * F + n0 + tx * 8;
        *reinterpret_cast<float4*>(G + base)     = o0;
        *reinterpret_cast<float4*>(G + base + 4) = o1;
        if (ACC) {
            *reinterpret_cast<float4*>(ACC + base)     = o0;
            *reinterpret_cast<float4*>(ACC + base + 4) = o1;
        }
    }
}

// ---------------- edge scatter: acc[dst] += g[src] (one wave per edge) ----------------
__global__ __launch_bounds__(256) void k_scatter(
    const float* __restrict__ g, float* __restrict__ acc,
    const int* __restrict__ src, const int* __restrict__ dst)
{
    int e = blockIdx.x * 4 + (threadIdx.x >> 6);
    if (e >= E_EDGES) return;
    int lane = threadIdx.x & 63;
    int s = src[e], d = dst[e];
    float4 v = *reinterpret_cast<const float4*>(g + (size_t)s * F + lane * 4);
    float* o = acc + (size_t)d * F + lane * 4;
    atomicAdd(o + 0, v.x);
    atomicAdd(o + 1, v.y);
    atomicAdd(o + 2, v.z);
    atomicAdd(o + 3, v.w);
}

// ---------------- finalize layer 1: h = relu(dis[d]*acc + b1) ----------------
__global__ void k_finalize_relu(const float* __restrict__ acc, const float* __restrict__ dis,
                                const float* __restrict__ b, float* __restrict__ h)
{
    size_t idx = (size_t)blockIdx.x * 256 + threadIdx.x;   // float4 index
    if (idx >= (size_t)N_NODES * 64) return;
    int d = (int)(idx >> 6);
    int q = (int)(idx & 63) * 4;
    float s = dis[d];
    float4 v  = *reinterpret_cast<const float4*>(acc + (size_t)d * F + q);
    float4 bb = *reinterpret_cast<const float4*>(b + q);
    float4 o;
    o.x = fmaxf(fmaf(s, v.x, bb.x), 0.0f);
    o.y = fmaxf(fmaf(s, v.y, bb.y), 0.0f);
    o.z = fmaxf(fmaf(s, v.z, bb.z), 0.0f);
    o.w = fmaxf(fmaf(s, v.w, bb.w), 0.0f);
    *reinterpret_cast<float4*>(h + (size_t)d * F + q) = o;
}

// ---------------- float4 copy ----------------
__global__ void k_copy(const float* __restrict__ in, float* __restrict__ out, long n4) {
    long i = (long)blockIdx.x * 256 + threadIdx.x;
    if (i < n4) reinterpret_cast<float4*>(out)[i] = reinterpret_cast<const float4*>(in)[i];
}

// ---------------- finalize layer 2: split into mu / logvar ----------------
__global__ void k_finalize_out(const float* __restrict__ acc, const float* __restrict__ dis,
                               const float* __restrict__ bmu, const float* __restrict__ blv,
                               float* __restrict__ out)
{
    size_t idx = (size_t)blockIdx.x * 256 + threadIdx.x;   // float4 index over N*64
    if (idx >= (size_t)N_NODES * 64) return;
    int d = (int)(idx >> 6);
    int q = (int)(idx & 63) * 4;
    float s = dis[d];
    float4 v = *reinterpret_cast<const float4*>(acc + (size_t)d * F + q);
    if (q < 128) {
        float4 bb = *reinterpret_cast<const float4*>(bmu + q);
        float4 o = make_float4(fmaf(s, v.x, bb.x), fmaf(s, v.y, bb.y),
                               fmaf(s, v.z, bb.z), fmaf(s, v.w, bb.w));
        *reinterpret_cast<float4*>(out + (size_t)d * 128 + q) = o;
    } else {
        int q2 = q - 128;
        float4 bb = *reinterpret_cast<const float4*>(blv + q2);
        float4 o = make_float4(fmaf(s, v.x, bb.x), fmaf(s, v.y, bb.y),
                               fmaf(s, v.z, bb.z), fmaf(s, v.w, bb.w));
        *reinterpret_cast<float4*>(out + LV_OFF + (size_t)d * 128 + q2) = o;
    }
}

extern "C" void kernel_launch(void* const* d_in, const int* in_sizes, int n_in,
                              void* d_out, int out_size, void* d_ws, size_t ws_size,
                              hipStream_t stream) {
    const float* x   = (const float*)d_in[0];
    const int*   ei  = (const int*)d_in[1];
    const int*   src = ei;
    const int*   dst = ei + E_EDGES;
    const float* W1  = (const float*)d_in[2];
    const float* b1  = (const float*)d_in[3];
    const float* Wmu = (const float*)d_in[4];
    const float* bmu = (const float*)d_in[5];
    const float* Wlv = (const float*)d_in[6];
    const float* blv = (const float*)d_in[7];
    float* out = (float*)d_out;

    char* ws = (char*)d_ws;
    float* dis  = (float*)ws;                      // 100000 floats = 400000 B (128-aligned size)
    float* Wcat = (float*)(ws + 400000);           // 256*256*4 = 262144 B
    const size_t BUF_OFF = 662528;                 // aligned past dis+Wcat
    const size_t BUF_BYTES = (size_t)N_NODES * F * 4;   // 102,400,000
    float* bufA = (float*)(ws + BUF_OFF);
    float* bufB;
    if (ws_size >= BUF_OFF + 2 * BUF_BYTES) {
        bufB = bufA + (size_t)N_NODES * F;
    } else {
        bufB = out;   // use output buffer as scratch; final write overwrites it last
    }

    // normalization (shared by all three convs)
    k_init_deg<<<(N_NODES + 255) / 256, 256, 0, stream>>>(dis);
    k_edge_deg<<<(E_EDGES + 255) / 256, 256, 0, stream>>>(dst, dis);
    k_dis<<<(N_NODES + 255) / 256, 256, 0, stream>>>(dis);
    k_wcat<<<256, 256, 0, stream>>>(Wmu, Wlv, Wcat);

    dim3 gemm_grid(782, 2);   // ceil(100000/128) x 256/128

    // layer 1: g1 = (x@W1)*dis -> bufA, acc1 (= g1 copy) -> bufB
    k_gemm_scaled<<<gemm_grid, 256, 0, stream>>>(x, W1, dis, bufA, bufB, N_NODES);
    k_scatter<<<E_EDGES / 4, 256, 0, stream>>>(bufA, bufB, src, dst);
    k_finalize_relu<<<25000, 256, 0, stream>>>(bufB, dis, b1, bufA);   // h -> bufA

    // layer 2 (mu|lv fused): g2 = (h@Wcat)*dis -> bufB
    k_gemm_scaled<<<gemm_grid, 256, 0, stream>>>(bufA, Wcat, dis, bufB, nullptr, N_NODES);
    k_copy<<<25000, 256, 0, stream>>>(bufB, bufA, 6400000);            // acc2 init (h is dead)
    k_scatter<<<E_EDGES / 4, 256, 0, stream>>>(bufB, bufA, src, dst);
    k_finalize_out<<<25000, 256, 0, stream>>>(bufA, dis, bmu, blv, out);
}

// Round 2
// 1014.836 us; speedup vs baseline: 10.9661x; 10.9661x over previous
//
#include <hip/hip_runtime.h>

#define N_NODES 100000
#define E_EDGES 1600000
#define F 256              // feature width at every stage (IN=256, HID=256, mu|lv = 256)
#define LV_OFF 12800000    // 100000*128
#define SCAN_BLK 98        // ceil(100000/1024)

// ---------------- zero int buffer ----------------
__global__ void k_zero(int* __restrict__ p, int n) {
    int i = blockIdx.x * 256 + threadIdx.x;
    if (i < n) p[i] = 0;
}

// ---------------- integer in-degree count (real edges only) ----------------
__global__ void k_count(const int* __restrict__ dst, int* __restrict__ cnt) {
    int e = blockIdx.x * 256 + threadIdx.x;
    if (e < E_EDGES) atomicAdd(&cnt[dst[e]], 1);
}

// ---------------- dis = rsqrt(deg + 1 self-loop) ----------------
__global__ void k_dis(const int* __restrict__ cnt, float* __restrict__ dis) {
    int i = blockIdx.x * 256 + threadIdx.x;
    if (i < N_NODES) dis[i] = rsqrtf((float)cnt[i] + 1.0f);
}

// ---------------- exclusive scan of cnt -> row_off (3 kernels) ----------------
// block covers 1024 nodes (256 threads x 4)
__global__ __launch_bounds__(256) void k_scan1(const int* __restrict__ cnt,
                                               int* __restrict__ row_off,
                                               int* __restrict__ bsum) {
    __shared__ int sd[256];
    int tid = threadIdx.x;
    int base = blockIdx.x * 1024 + tid * 4;
    int c[4]; int s = 0;
#pragma unroll
    for (int k = 0; k < 4; k++) {
        int i = base + k;
        c[k] = (i < N_NODES) ? cnt[i] : 0;
        s += c[k];
    }
    sd[tid] = s;
    __syncthreads();
    for (int off = 1; off < 256; off <<= 1) {
        int t = (tid >= off) ? sd[tid - off] : 0;
        __syncthreads();
        sd[tid] += t;
        __syncthreads();
    }
    int run = sd[tid] - s;   // exclusive prefix of this thread's chunk within block
#pragma unroll
    for (int k = 0; k < 4; k++) {
        int i = base + k;
        if (i < N_NODES) row_off[i] = run;
        run += c[k];
    }
    if (tid == 255) bsum[blockIdx.x] = sd[255];
}

__global__ void k_scan2(int* __restrict__ bsum) {
    if (threadIdx.x == 0 && blockIdx.x == 0) {
        int run = 0;
        for (int i = 0; i < SCAN_BLK; ++i) { int t = bsum[i]; bsum[i] = run; run += t; }
    }
}

__global__ __launch_bounds__(256) void k_scan3(int* __restrict__ row_off,
                                               const int* __restrict__ bsum,
                                               int* __restrict__ cursor) {
    int tid = threadIdx.x;
    int add = bsum[blockIdx.x];
    int base = blockIdx.x * 1024 + tid * 4;
#pragma unroll
    for (int k = 0; k < 4; k++) {
        int i = base + k;
        if (i < N_NODES) {
            int v = row_off[i] + add;
            row_off[i] = v;
            cursor[i] = v;
        }
    }
    if (blockIdx.x == 0 && tid == 0) row_off[N_NODES] = E_EDGES;
}

// ---------------- CSR fill: bucket srcs by dst ----------------
__global__ void k_fill(const int* __restrict__ src, const int* __restrict__ dst,
                       int* __restrict__ cursor, int* __restrict__ csr_src) {
    int e = blockIdx.x * 256 + threadIdx.x;
    if (e < E_EDGES) {
        int pos = atomicAdd(&cursor[dst[e]], 1);
        csr_src[pos] = src[e];
    }
}

// ---------------- build concatenated [W_mu | W_lv] ----------------
__global__ void k_wcat(const float* __restrict__ Wmu, const float* __restrict__ Wlv,
                       float* __restrict__ Wcat) {
    int idx = blockIdx.x * 256 + threadIdx.x;   // 256*256 elements
    int k = idx >> 8, j = idx & 255;
    Wcat[idx] = (j < 128) ? Wmu[k * 128 + j] : Wlv[k * 128 + (j - 128)];
}

// ---------------- fp32 tiled GEMM, epilogue scales by dis[row] ----------------
__global__ __launch_bounds__(256) void k_gemm_scaled(
    const float* __restrict__ A, const float* __restrict__ B,
    const float* __restrict__ dis,
    float* __restrict__ G, int M)
{
    __shared__ float As[16][132];
    __shared__ float Bs[16][128];

    const int tid = threadIdx.x;
    const int tx = tid & 15, ty = tid >> 4;
    const int m0 = blockIdx.x * 128;
    const int n0 = blockIdx.y * 128;

    float acc[8][8];
#pragma unroll
    for (int i = 0; i < 8; i++)
#pragma unroll
        for (int j = 0; j < 8; j++) acc[i][j] = 0.0f;

    const int arow0 = tid >> 2;
    const int aq    = tid & 3;

    for (int kt = 0; kt < 256; kt += 16) {
#pragma unroll
        for (int h = 0; h < 2; ++h) {
            int row = arow0 + h * 64;
            int gm = m0 + row; if (gm >= M) gm = M - 1;
            float4 v = *reinterpret_cast<const float4*>(A + (size_t)gm * F + kt + aq * 4);
            As[aq * 4 + 0][row] = v.x;
            As[aq * 4 + 1][row] = v.y;
            As[aq * 4 + 2][row] = v.z;
            As[aq * 4 + 3][row] = v.w;
        }
#pragma unroll
        for (int h = 0; h < 2; ++h) {
            int l = tid + h * 256;
            int r = l >> 5, cq = l & 31;
            float4 v = *reinterpret_cast<const float4*>(B + (size_t)(kt + r) * F + n0 + cq * 4);
            *reinterpret_cast<float4*>(&Bs[r][cq * 4]) = v;
        }
        __syncthreads();
#pragma unroll
        for (int k = 0; k < 16; k++) {
            float4 a0 = *reinterpret_cast<const float4*>(&As[k][ty * 8]);
            float4 a1 = *reinterpret_cast<const float4*>(&As[k][ty * 8 + 4]);
            float4 b0 = *reinterpret_cast<const float4*>(&Bs[k][tx * 8]);
            float4 b1 = *reinterpret_cast<const float4*>(&Bs[k][tx * 8 + 4]);
            float av[8] = {a0.x, a0.y, a0.z, a0.w, a1.x, a1.y, a1.z, a1.w};
            float bv[8] = {b0.x, b0.y, b0.z, b0.w, b1.x, b1.y, b1.z, b1.w};
#pragma unroll
            for (int i = 0; i < 8; i++)
#pragma unroll
                for (int j = 0; j < 8; j++)
                    acc[i][j] = fmaf(av[i], bv[j], acc[i][j]);
        }
        __syncthreads();
    }

#pragma unroll
    for (int i = 0; i < 8; i++) {
        int m = m0 + ty * 8 + i;
        if (m >= M) continue;
        float s = dis[m];
        float4 o0 = make_float4(acc[i][0] * s, acc[i][1] * s, acc[i][2] * s, acc[i][3] * s);
        float4 o1 = make_float4(acc[i][4] * s, acc[i][5] * s, acc[i][6] * s, acc[i][7] * s);
        size_t base = (size_t)m * F + n0 + tx * 8;
        *reinterpret_cast<float4*>(G + base)     = o0;
        *reinterpret_cast<float4*>(G + base + 4) = o1;
    }
}

// ---------------- CSR gather aggregate, layer-1 epilogue (relu) ----------------
// one wave per node; 64 lanes x float4 = 256 channels
__global__ __launch_bounds__(256) void k_aggregate_relu(
    const float* __restrict__ g, const int* __restrict__ row_off,
    const int* __restrict__ csr_src, const float* __restrict__ dis,
    const float* __restrict__ b, float* __restrict__ h)
{
    int d = blockIdx.x * 4 + (threadIdx.x >> 6);
    int lane = threadIdx.x & 63;
    const float4* g4 = reinterpret_cast<const float4*>(g);
    float4 acc = g4[(size_t)d * 64 + lane];   // self-loop term
    float4 acc2 = make_float4(0.f, 0.f, 0.f, 0.f);
    int j0 = row_off[d], j1 = row_off[d + 1];
    int j = j0;
    for (; j + 1 < j1; j += 2) {
        int s0 = csr_src[j], s1 = csr_src[j + 1];
        float4 v0 = g4[(size_t)s0 * 64 + lane];
        float4 v1 = g4[(size_t)s1 * 64 + lane];
        acc.x += v0.x; acc.y += v0.y; acc.z += v0.z; acc.w += v0.w;
        acc2.x += v1.x; acc2.y += v1.y; acc2.z += v1.z; acc2.w += v1.w;
    }
    if (j < j1) {
        int s0 = csr_src[j];
        float4 v0 = g4[(size_t)s0 * 64 + lane];
        acc.x += v0.x; acc.y += v0.y; acc.z += v0.z; acc.w += v0.w;
    }
    acc.x += acc2.x; acc.y += acc2.y; acc.z += acc2.z; acc.w += acc2.w;
    float sc = dis[d];
    float4 bb = reinterpret_cast<const float4*>(b)[lane];
    float4 o;
    o.x = fmaxf(fmaf(sc, acc.x, bb.x), 0.0f);
    o.y = fmaxf(fmaf(sc, acc.y, bb.y), 0.0f);
    o.z = fmaxf(fmaf(sc, acc.z, bb.z), 0.0f);
    o.w = fmaxf(fmaf(sc, acc.w, bb.w), 0.0f);
    reinterpret_cast<float4*>(h)[(size_t)d * 64 + lane] = o;
}

// ---------------- CSR gather aggregate, layer-2 epilogue (mu | logvar split) ----------------
__global__ __launch_bounds__(256) void k_aggregate_out(
    const float* __restrict__ g, const int* __restrict__ row_off,
    const int* __restrict__ csr_src, const float* __restrict__ dis,
    const float* __restrict__ bmu, const float* __restrict__ blv,
    float* __restrict__ out)
{
    int d = blockIdx.x * 4 + (threadIdx.x >> 6);
    int lane = threadIdx.x & 63;
    const float4* g4 = reinterpret_cast<const float4*>(g);
    float4 acc = g4[(size_t)d * 64 + lane];
    float4 acc2 = make_float4(0.f, 0.f, 0.f, 0.f);
    int j0 = row_off[d], j1 = row_off[d + 1];
    int j = j0;
    for (; j + 1 < j1; j += 2) {
        int s0 = csr_src[j], s1 = csr_src[j + 1];
        float4 v0 = g4[(size_t)s0 * 64 + lane];
        float4 v1 = g4[(size_t)s1 * 64 + lane];
        acc.x += v0.x; acc.y += v0.y; acc.z += v0.z; acc.w += v0.w;
        acc2.x += v1.x; acc2.y += v1.y; acc2.z += v1.z; acc2.w += v1.w;
    }
    if (j < j1) {
        int s0 = csr_src[j];
        float4 v0 = g4[(size_t)s0 * 64 + lane];
        acc.x += v0.x; acc.y += v0.y; acc.z += v0.z; acc.w += v0.w;
    }
    acc.x += acc2.x; acc.y += acc2.y; acc.z += acc2.z; acc.w += acc2.w;
    float sc = dis[d];
    if (lane < 32) {
        float4 bb = reinterpret_cast<const float4*>(bmu)[lane];
        float4 o = make_float4(fmaf(sc, acc.x, bb.x), fmaf(sc, acc.y, bb.y),
                               fmaf(sc, acc.z, bb.z), fmaf(sc, acc.w, bb.w));
        reinterpret_cast<float4*>(out)[(size_t)d * 32 + lane] = o;
    } else {
        int l2 = lane - 32;
        float4 bb = reinterpret_cast<const float4*>(blv)[l2];
        float4 o = make_float4(fmaf(sc, acc.x, bb.x), fmaf(sc, acc.y, bb.y),
                               fmaf(sc, acc.z, bb.z), fmaf(sc, acc.w, bb.w));
        reinterpret_cast<float4*>(out + LV_OFF)[(size_t)d * 32 + l2] = o;
    }
}

extern "C" void kernel_launch(void* const* d_in, const int* in_sizes, int n_in,
                              void* d_out, int out_size, void* d_ws, size_t ws_size,
                              hipStream_t stream) {
    const float* x   = (const float*)d_in[0];
    const int*   ei  = (const int*)d_in[1];
    const int*   src = ei;
    const int*   dst = ei + E_EDGES;
    const float* W1  = (const float*)d_in[2];
    const float* b1  = (const float*)d_in[3];
    const float* Wmu = (const float*)d_in[4];
    const float* bmu = (const float*)d_in[5];
    const float* Wlv = (const float*)d_in[6];
    const float* blv = (const float*)d_in[7];
    float* out = (float*)d_out;

    // workspace carve-up (1 KiB aligned)
    char* ws = (char*)d_ws;
    size_t o = 0;
    auto carve = [&](size_t bytes) -> char* {
        char* p = ws + o;
        o = (o + bytes + 1023) & ~(size_t)1023;
        return p;
    };
    float* dis     = (float*)carve(400000);                 // N floats
    float* Wcat    = (float*)carve(262144);                 // 256*256
    int*   cnt     = (int*)  carve(400000);                 // N ints (also reused as nothing after dis)
    int*   row_off = (int*)  carve(400004);                 // N+1 ints
    int*   cursor  = (int*)  carve(400000);                 // N ints
    int*   bsum    = (int*)  carve(SCAN_BLK * 4);           // scan partials
    int*   csr_src = (int*)  carve((size_t)E_EDGES * 4);    // 6.4 MB
    float* g       = (float*)carve((size_t)N_NODES * F * 4);// 102.4 MB
    (void)ws_size;

    // ---- graph preprocessing (once per call, reused by both aggregations) ----
    k_zero <<<(N_NODES + 255) / 256, 256, 0, stream>>>(cnt, N_NODES);
    k_count<<<(E_EDGES + 255) / 256, 256, 0, stream>>>(dst, cnt);
    k_dis  <<<(N_NODES + 255) / 256, 256, 0, stream>>>(cnt, dis);
    k_scan1<<<SCAN_BLK, 256, 0, stream>>>(cnt, row_off, bsum);
    k_scan2<<<1, 64, 0, stream>>>(bsum);
    k_scan3<<<SCAN_BLK, 256, 0, stream>>>(row_off, bsum, cursor);
    k_fill <<<(E_EDGES + 255) / 256, 256, 0, stream>>>(src, dst, cursor, csr_src);
    k_wcat <<<256, 256, 0, stream>>>(Wmu, Wlv, Wcat);

    dim3 gemm_grid(782, 2);   // ceil(100000/128) x 256/128

    // layer 1: g = (x@W1)*dis ; h = relu(dis*(g[self]+sum g[nbr]) + b1) -> d_out (temp)
    k_gemm_scaled   <<<gemm_grid, 256, 0, stream>>>(x, W1, dis, g, N_NODES);
    k_aggregate_relu<<<N_NODES / 4, 256, 0, stream>>>(g, row_off, csr_src, dis, b1, out);

    // layer 2 (mu|lv fused): g = (h@Wcat)*dis ; out = dis*(g[self]+sum g[nbr]) + b
    k_gemm_scaled   <<<gemm_grid, 256, 0, stream>>>(out, Wcat, dis, g, N_NODES);
    k_aggregate_out <<<N_NODES / 4, 256, 0, stream>>>(g, row_off, csr_src, dis, bmu, blv, out);
}

// Round 3
// 769.041 us; speedup vs baseline: 14.4709x; 1.3196x over previous
//
#include <hip/hip_runtime.h>
#include <hip/hip_fp16.h>

#define N_NODES 100000
#define E_EDGES 1600000
#define F 256              // feature width at every stage (IN=256, HID=256, mu|lv = 256)
#define LV_OFF 12800000    // 100000*128
#define SCAN_BLK 98        // ceil(100000/1024)

typedef _Float16 half8 __attribute__((ext_vector_type(8)));
typedef _Float16 half4 __attribute__((ext_vector_type(4)));

// ---------------- zero int buffer ----------------
__global__ void k_zero(int* __restrict__ p, int n) {
    int i = blockIdx.x * 256 + threadIdx.x;
    if (i < n) p[i] = 0;
}

// ---------------- integer in-degree count (real edges only) ----------------
__global__ void k_count(const int* __restrict__ dst, int* __restrict__ cnt) {
    int e = blockIdx.x * 256 + threadIdx.x;
    if (e < E_EDGES) atomicAdd(&cnt[dst[e]], 1);
}

// ---------------- dis = rsqrt(deg + 1 self-loop) ----------------
__global__ void k_dis(const int* __restrict__ cnt, float* __restrict__ dis) {
    int i = blockIdx.x * 256 + threadIdx.x;
    if (i < N_NODES) dis[i] = rsqrtf((float)cnt[i] + 1.0f);
}

// ---------------- exclusive scan of cnt -> row_off (3 kernels) ----------------
__global__ __launch_bounds__(256) void k_scan1(const int* __restrict__ cnt,
                                               int* __restrict__ row_off,
                                               int* __restrict__ bsum) {
    __shared__ int sd[256];
    int tid = threadIdx.x;
    int base = blockIdx.x * 1024 + tid * 4;
    int c[4]; int s = 0;
#pragma unroll
    for (int k = 0; k < 4; k++) {
        int i = base + k;
        c[k] = (i < N_NODES) ? cnt[i] : 0;
        s += c[k];
    }
    sd[tid] = s;
    __syncthreads();
    for (int off = 1; off < 256; off <<= 1) {
        int t = (tid >= off) ? sd[tid - off] : 0;
        __syncthreads();
        sd[tid] += t;
        __syncthreads();
    }
    int run = sd[tid] - s;
#pragma unroll
    for (int k = 0; k < 4; k++) {
        int i = base + k;
        if (i < N_NODES) row_off[i] = run;
        run += c[k];
    }
    if (tid == 255) bsum[blockIdx.x] = sd[255];
}

__global__ void k_scan2(int* __restrict__ bsum) {
    if (threadIdx.x == 0 && blockIdx.x == 0) {
        int run = 0;
        for (int i = 0; i < SCAN_BLK; ++i) { int t = bsum[i]; bsum[i] = run; run += t; }
    }
}

__global__ __launch_bounds__(256) void k_scan3(int* __restrict__ row_off,
                                               const int* __restrict__ bsum,
                                               int* __restrict__ cursor) {
    int tid = threadIdx.x;
    int add = bsum[blockIdx.x];
    int base = blockIdx.x * 1024 + tid * 4;
#pragma unroll
    for (int k = 0; k < 4; k++) {
        int i = base + k;
        if (i < N_NODES) {
            int v = row_off[i] + add;
            row_off[i] = v;
            cursor[i] = v;
        }
    }
    if (blockIdx.x == 0 && tid == 0) row_off[N_NODES] = E_EDGES;
}

// ---------------- CSR fill: bucket srcs by dst ----------------
__global__ void k_fill(const int* __restrict__ src, const int* __restrict__ dst,
                       int* __restrict__ cursor, int* __restrict__ csr_src) {
    int e = blockIdx.x * 256 + threadIdx.x;
    if (e < E_EDGES) {
        int pos = atomicAdd(&cursor[dst[e]], 1);
        csr_src[pos] = src[e];
    }
}

// ---------------- build concatenated [W_mu | W_lv] ----------------
__global__ void k_wcat(const float* __restrict__ Wmu, const float* __restrict__ Wlv,
                       float* __restrict__ Wcat) {
    int idx = blockIdx.x * 256 + threadIdx.x;
    int k = idx >> 8, j = idx & 255;
    Wcat[idx] = (j < 128) ? Wmu[k * 128 + j] : Wlv[k * 128 + (j - 128)];
}

// ---------------- fp32 tiled GEMM, epilogue scales by dis[row], writes fp16 ----------------
__global__ __launch_bounds__(256) void k_gemm_scaled(
    const float* __restrict__ A, const float* __restrict__ B,
    const float* __restrict__ dis,
    _Float16* __restrict__ G, int M)
{
    __shared__ float As[16][132];
    __shared__ float Bs[16][128];

    const int tid = threadIdx.x;
    const int tx = tid & 15, ty = tid >> 4;
    const int m0 = blockIdx.x * 128;
    const int n0 = blockIdx.y * 128;

    float acc[8][8];
#pragma unroll
    for (int i = 0; i < 8; i++)
#pragma unroll
        for (int j = 0; j < 8; j++) acc[i][j] = 0.0f;

    const int arow0 = tid >> 2;
    const int aq    = tid & 3;

    for (int kt = 0; kt < 256; kt += 16) {
#pragma unroll
        for (int h = 0; h < 2; ++h) {
            int row = arow0 + h * 64;
            int gm = m0 + row; if (gm >= M) gm = M - 1;
            float4 v = *reinterpret_cast<const float4*>(A + (size_t)gm * F + kt + aq * 4);
            As[aq * 4 + 0][row] = v.x;
            As[aq * 4 + 1][row] = v.y;
            As[aq * 4 + 2][row] = v.z;
            As[aq * 4 + 3][row] = v.w;
        }
#pragma unroll
        for (int h = 0; h < 2; ++h) {
            int l = tid + h * 256;
            int r = l >> 5, cq = l & 31;
            float4 v = *reinterpret_cast<const float4*>(B + (size_t)(kt + r) * F + n0 + cq * 4);
            *reinterpret_cast<float4*>(&Bs[r][cq * 4]) = v;
        }
        __syncthreads();
#pragma unroll
        for (int k = 0; k < 16; k++) {
            float4 a0 = *reinterpret_cast<const float4*>(&As[k][ty * 8]);
            float4 a1 = *reinterpret_cast<const float4*>(&As[k][ty * 8 + 4]);
            float4 b0 = *reinterpret_cast<const float4*>(&Bs[k][tx * 8]);
            float4 b1 = *reinterpret_cast<const float4*>(&Bs[k][tx * 8 + 4]);
            float av[8] = {a0.x, a0.y, a0.z, a0.w, a1.x, a1.y, a1.z, a1.w};
            float bv[8] = {b0.x, b0.y, b0.z, b0.w, b1.x, b1.y, b1.z, b1.w};
#pragma unroll
            for (int i = 0; i < 8; i++)
#pragma unroll
                for (int j = 0; j < 8; j++)
                    acc[i][j] = fmaf(av[i], bv[j], acc[i][j]);
        }
        __syncthreads();
    }

#pragma unroll
    for (int i = 0; i < 8; i++) {
        int m = m0 + ty * 8 + i;
        if (m >= M) continue;
        float s = dis[m];
        half8 o;
#pragma unroll
        for (int j = 0; j < 8; j++) o[j] = (_Float16)(acc[i][j] * s);
        *reinterpret_cast<half8*>(G + (size_t)m * F + n0 + tx * 8) = o;
    }
}

// ---------------- CSR gather aggregate (fp16 g, fp32 accum), layer-1 epilogue ----------------
// one wave per node; 64 lanes x half4 = 256 channels
__global__ __launch_bounds__(256) void k_aggregate_relu(
    const _Float16* __restrict__ g, const int* __restrict__ row_off,
    const int* __restrict__ csr_src, const float* __restrict__ dis,
    const float* __restrict__ b, float* __restrict__ h)
{
    int d = blockIdx.x * 4 + (threadIdx.x >> 6);
    int lane = threadIdx.x & 63;
    const half4* g4 = reinterpret_cast<const half4*>(g);
    half4 sv = g4[(size_t)d * 64 + lane];   // self-loop term
    float a0 = (float)sv[0], a1 = (float)sv[1], a2 = (float)sv[2], a3 = (float)sv[3];
    float b0 = 0.f, b1v = 0.f, b2 = 0.f, b3 = 0.f;
    float c0 = 0.f, c1 = 0.f, c2 = 0.f, c3 = 0.f;
    float e0 = 0.f, e1 = 0.f, e2 = 0.f, e3 = 0.f;
    int j0 = row_off[d], j1 = row_off[d + 1];
    int j = j0;
    for (; j + 3 < j1; j += 4) {
        int s0 = csr_src[j], s1 = csr_src[j + 1], s2 = csr_src[j + 2], s3 = csr_src[j + 3];
        half4 v0 = g4[(size_t)s0 * 64 + lane];
        half4 v1 = g4[(size_t)s1 * 64 + lane];
        half4 v2 = g4[(size_t)s2 * 64 + lane];
        half4 v3 = g4[(size_t)s3 * 64 + lane];
        a0 += (float)v0[0]; a1 += (float)v0[1]; a2 += (float)v0[2]; a3 += (float)v0[3];
        b0 += (float)v1[0]; b1v += (float)v1[1]; b2 += (float)v1[2]; b3 += (float)v1[3];
        c0 += (float)v2[0]; c1 += (float)v2[1]; c2 += (float)v2[2]; c3 += (float)v2[3];
        e0 += (float)v3[0]; e1 += (float)v3[1]; e2 += (float)v3[2]; e3 += (float)v3[3];
    }
    for (; j < j1; ++j) {
        int s0 = csr_src[j];
        half4 v0 = g4[(size_t)s0 * 64 + lane];
        a0 += (float)v0[0]; a1 += (float)v0[1]; a2 += (float)v0[2]; a3 += (float)v0[3];
    }
    a0 += b0 + c0 + e0; a1 += b1v + c1 + e1; a2 += b2 + c2 + e2; a3 += b3 + c3 + e3;
    float sc = dis[d];
    float4 bb = reinterpret_cast<const float4*>(b)[lane];
    float4 o;
    o.x = fmaxf(fmaf(sc, a0, bb.x), 0.0f);
    o.y = fmaxf(fmaf(sc, a1, bb.y), 0.0f);
    o.z = fmaxf(fmaf(sc, a2, bb.z), 0.0f);
    o.w = fmaxf(fmaf(sc, a3, bb.w), 0.0f);
    reinterpret_cast<float4*>(h)[(size_t)d * 64 + lane] = o;
}

// ---------------- CSR gather aggregate, layer-2 epilogue (mu | logvar split) ----------------
__global__ __launch_bounds__(256) void k_aggregate_out(
    const _Float16* __restrict__ g, const int* __restrict__ row_off,
    const int* __restrict__ csr_src, const float* __restrict__ dis,
    const float* __restrict__ bmu, const float* __restrict__ blv,
    float* __restrict__ out)
{
    int d = blockIdx.x * 4 + (threadIdx.x >> 6);
    int lane = threadIdx.x & 63;
    const half4* g4 = reinterpret_cast<const half4*>(g);
    half4 sv = g4[(size_t)d * 64 + lane];
    float a0 = (float)sv[0], a1 = (float)sv[1], a2 = (float)sv[2], a3 = (float)sv[3];
    float b0 = 0.f, b1v = 0.f, b2 = 0.f, b3 = 0.f;
    float c0 = 0.f, c1 = 0.f, c2 = 0.f, c3 = 0.f;
    float e0 = 0.f, e1 = 0.f, e2 = 0.f, e3 = 0.f;
    int j0 = row_off[d], j1 = row_off[d + 1];
    int j = j0;
    for (; j + 3 < j1; j += 4) {
        int s0 = csr_src[j], s1 = csr_src[j + 1], s2 = csr_src[j + 2], s3 = csr_src[j + 3];
        half4 v0 = g4[(size_t)s0 * 64 + lane];
        half4 v1 = g4[(size_t)s1 * 64 + lane];
        half4 v2 = g4[(size_t)s2 * 64 + lane];
        half4 v3 = g4[(size_t)s3 * 64 + lane];
        a0 += (float)v0[0]; a1 += (float)v0[1]; a2 += (float)v0[2]; a3 += (float)v0[3];
        b0 += (float)v1[0]; b1v += (float)v1[1]; b2 += (float)v1[2]; b3 += (float)v1[3];
        c0 += (float)v2[0]; c1 += (float)v2[1]; c2 += (float)v2[2]; c3 += (float)v2[3];
        e0 += (float)v3[0]; e1 += (float)v3[1]; e2 += (float)v3[2]; e3 += (float)v3[3];
    }
    for (; j < j1; ++j) {
        int s0 = csr_src[j];
        half4 v0 = g4[(size_t)s0 * 64 + lane];
        a0 += (float)v0[0]; a1 += (float)v0[1]; a2 += (float)v0[2]; a3 += (float)v0[3];
    }
    a0 += b0 + c0 + e0; a1 += b1v + c1 + e1; a2 += b2 + c2 + e2; a3 += b3 + c3 + e3;
    float sc = dis[d];
    if (lane < 32) {
        float4 bb = reinterpret_cast<const float4*>(bmu)[lane];
        float4 o = make_float4(fmaf(sc, a0, bb.x), fmaf(sc, a1, bb.y),
                               fmaf(sc, a2, bb.z), fmaf(sc, a3, bb.w));
        reinterpret_cast<float4*>(out)[(size_t)d * 32 + lane] = o;
    } else {
        int l2 = lane - 32;
        float4 bb = reinterpret_cast<const float4*>(blv)[l2];
        float4 o = make_float4(fmaf(sc, a0, bb.x), fmaf(sc, a1, bb.y),
                               fmaf(sc, a2, bb.z), fmaf(sc, a3, bb.w));
        reinterpret_cast<float4*>(out + LV_OFF)[(size_t)d * 32 + l2] = o;
    }
}

extern "C" void kernel_launch(void* const* d_in, const int* in_sizes, int n_in,
                              void* d_out, int out_size, void* d_ws, size_t ws_size,
                              hipStream_t stream) {
    const float* x   = (const float*)d_in[0];
    const int*   ei  = (const int*)d_in[1];
    const int*   src = ei;
    const int*   dst = ei + E_EDGES;
    const float* W1  = (const float*)d_in[2];
    const float* b1  = (const float*)d_in[3];
    const float* Wmu = (const float*)d_in[4];
    const float* bmu = (const float*)d_in[5];
    const float* Wlv = (const float*)d_in[6];
    const float* blv = (const float*)d_in[7];
    float* out = (float*)d_out;

    // workspace carve-up (1 KiB aligned)
    char* ws = (char*)d_ws;
    size_t o = 0;
    auto carve = [&](size_t bytes) -> char* {
        char* p = ws + o;
        o = (o + bytes + 1023) & ~(size_t)1023;
        return p;
    };
    float*    dis     = (float*)   carve(400000);
    float*    Wcat    = (float*)   carve(262144);
    int*      cnt     = (int*)     carve(400000);
    int*      row_off = (int*)     carve(400004);
    int*      cursor  = (int*)     carve(400000);
    int*      bsum    = (int*)     carve(SCAN_BLK * 4);
    int*      csr_src = (int*)     carve((size_t)E_EDGES * 4);       // 6.4 MB
    _Float16* g       = (_Float16*)carve((size_t)N_NODES * F * 2);   // 51.2 MB fp16
    (void)ws_size;

    // ---- graph preprocessing (once per call, reused by both aggregations) ----
    k_zero <<<(N_NODES + 255) / 256, 256, 0, stream>>>(cnt, N_NODES);
    k_count<<<(E_EDGES + 255) / 256, 256, 0, stream>>>(dst, cnt);
    k_dis  <<<(N_NODES + 255) / 256, 256, 0, stream>>>(cnt, dis);
    k_scan1<<<SCAN_BLK, 256, 0, stream>>>(cnt, row_off, bsum);
    k_scan2<<<1, 64, 0, stream>>>(bsum);
    k_scan3<<<SCAN_BLK, 256, 0, stream>>>(row_off, bsum, cursor);
    k_fill <<<(E_EDGES + 255) / 256, 256, 0, stream>>>(src, dst, cursor, csr_src);
    k_wcat <<<256, 256, 0, stream>>>(Wmu, Wlv, Wcat);

    dim3 gemm_grid(782, 2);   // ceil(100000/128) x 256/128

    // layer 1: g = fp16((x@W1)*dis) ; h = relu(dis*(g[self]+sum g[nbr]) + b1) -> d_out (temp)
    k_gemm_scaled   <<<gemm_grid, 256, 0, stream>>>(x, W1, dis, g, N_NODES);
    k_aggregate_relu<<<N_NODES / 4, 256, 0, stream>>>(g, row_off, csr_src, dis, b1, out);

    // layer 2 (mu|lv fused): g = fp16((h@Wcat)*dis) ; out = dis*(g[self]+sum g[nbr]) + b
    k_gemm_scaled   <<<gemm_grid, 256, 0, stream>>>(out, Wcat, dis, g, N_NODES);
    k_aggregate_out <<<N_NODES / 4, 256, 0, stream>>>(g, row_off, csr_src, dis, bmu, blv, out);
}

// Round 5
// 670.673 us; speedup vs baseline: 16.5934x; 1.1467x over previous
//
#include <hip/hip_runtime.h>
#include <hip/hip_fp16.h>

#define N_NODES 100000
#define E_EDGES 1600000
#define F 256              // feature width at every stage
#define LV_OFF 12800000    // 100000*128
#define SCAN_BLK 98        // ceil(100000/1024)

typedef _Float16 half8 __attribute__((ext_vector_type(8)));
typedef short    s16x4 __attribute__((ext_vector_type(4)));
typedef short    s16x8 __attribute__((ext_vector_type(8)));
typedef float    f32x4 __attribute__((ext_vector_type(4)));

// round-to-nearest-even fp32 -> bf16 split: x ~= hi + lo.
// returns packed: low 16 bits = hi bf16, high 16 bits = lo bf16
__device__ __forceinline__ unsigned split_bf16(float x) {
    unsigned u = __float_as_uint(x);
    unsigned r = (u + 0x7FFFu + ((u >> 16) & 1u)) >> 16;
    float fhi = __uint_as_float(r << 16);
    float rl = x - fhi;
    unsigned u2 = __float_as_uint(rl);
    unsigned l = (u2 + 0x7FFFu + ((u2 >> 16) & 1u)) >> 16;
    return (r & 0xFFFFu) | (l << 16);
}

// ---------------- small prep kernels ----------------
__global__ void k_zero(int* __restrict__ p, int n) {
    int i = blockIdx.x * 256 + threadIdx.x;
    if (i < n) p[i] = 0;
}

__global__ void k_count(const int* __restrict__ dst, int* __restrict__ cnt) {
    int e = blockIdx.x * 256 + threadIdx.x;
    if (e < E_EDGES) atomicAdd(&cnt[dst[e]], 1);
}

__global__ void k_dis(const int* __restrict__ cnt, float* __restrict__ dis) {
    int i = blockIdx.x * 256 + threadIdx.x;
    if (i < N_NODES) dis[i] = rsqrtf((float)cnt[i] + 1.0f);
}

__global__ __launch_bounds__(256) void k_scan1(const int* __restrict__ cnt,
                                               int* __restrict__ row_off,
                                               int* __restrict__ bsum) {
    __shared__ int sd[256];
    int tid = threadIdx.x;
    int base = blockIdx.x * 1024 + tid * 4;
    int c[4]; int s = 0;
#pragma unroll
    for (int k = 0; k < 4; k++) {
        int i = base + k;
        c[k] = (i < N_NODES) ? cnt[i] : 0;
        s += c[k];
    }
    sd[tid] = s;
    __syncthreads();
    for (int off = 1; off < 256; off <<= 1) {
        int t = (tid >= off) ? sd[tid - off] : 0;
        __syncthreads();
        sd[tid] += t;
        __syncthreads();
    }
    int run = sd[tid] - s;
#pragma unroll
    for (int k = 0; k < 4; k++) {
        int i = base + k;
        if (i < N_NODES) row_off[i] = run;
        run += c[k];
    }
    if (tid == 255) bsum[blockIdx.x] = sd[255];
}

__global__ void k_scan2(int* __restrict__ bsum) {
    if (threadIdx.x == 0 && blockIdx.x == 0) {
        int run = 0;
        for (int i = 0; i < SCAN_BLK; ++i) { int t = bsum[i]; bsum[i] = run; run += t; }
    }
}

__global__ __launch_bounds__(256) void k_scan3(int* __restrict__ row_off,
                                               const int* __restrict__ bsum,
                                               int* __restrict__ cursor) {
    int tid = threadIdx.x;
    int add = bsum[blockIdx.x];
    int base = blockIdx.x * 1024 + tid * 4;
#pragma unroll
    for (int k = 0; k < 4; k++) {
        int i = base + k;
        if (i < N_NODES) {
            int v = row_off[i] + add;
            row_off[i] = v;
            cursor[i] = v;
        }
    }
    if (blockIdx.x == 0 && tid == 0) row_off[N_NODES] = E_EDGES;
}

__global__ void k_fill(const int* __restrict__ src, const int* __restrict__ dst,
                       int* __restrict__ cursor, int* __restrict__ csr_src) {
    int e = blockIdx.x * 256 + threadIdx.x;
    if (e < E_EDGES) {
        int pos = atomicAdd(&cursor[dst[e]], 1);
        csr_src[pos] = src[e];
    }
}

// build transposed hi/lo bf16 weights: Wt1[n][k] from W1[k][n]; Wtc[n][k] from Wmu|Wlv
__global__ void k_wprep(const float* __restrict__ W1,
                        const float* __restrict__ Wmu, const float* __restrict__ Wlv,
                        short* __restrict__ Wt1h, short* __restrict__ Wt1l,
                        short* __restrict__ Wtch, short* __restrict__ Wtcl) {
    int idx = blockIdx.x * 256 + threadIdx.x;   // 65536
    int n = idx >> 8, k = idx & 255;
    float w1 = W1[k * 256 + n];
    float wc = (n < 128) ? Wmu[k * 128 + n] : Wlv[k * 128 + (n - 128)];
    unsigned p1 = split_bf16(w1);
    unsigned pc = split_bf16(wc);
    Wt1h[n * 256 + k] = (short)(p1 & 0xFFFFu);
    Wt1l[n * 256 + k] = (short)(p1 >> 16);
    Wtch[n * 256 + k] = (short)(pc & 0xFFFFu);
    Wtcl[n * 256 + k] = (short)(pc >> 16);
}

// ---------------- MFMA GEMM (split-bf16, fp32-accurate), epilogue *dis[m], fp16 out ----------------
// A fp32 [M,256] row-major; Bt* bf16 [256n][256k] (transposed, hi/lo); G fp16 [M,256].
__global__ __launch_bounds__(256) void k_gemm_mfma(
    const float* __restrict__ A,
    const short* __restrict__ Bth, const short* __restrict__ Btl,
    const float* __restrict__ dis, _Float16* __restrict__ G, int M)
{
    __shared__ short Ah[128 * 64];   // [row][k] swizzled, 16KB
    __shared__ short Al[128 * 64];
    __shared__ short Bh[128 * 64];   // [col][k] swizzled
    __shared__ short Bl[128 * 64];

    const int tid  = threadIdx.x;
    const int m0   = blockIdx.x * 128;
    const int n0   = blockIdx.y * 128;
    const int wave = tid >> 6, lane = tid & 63;
    const int wm   = wave & 1, wn = wave >> 1;
    const int lrow = lane & 15, kgrp = lane >> 4;

    f32x4 acc[4][4];
#pragma unroll
    for (int i = 0; i < 4; i++)
#pragma unroll
        for (int j = 0; j < 4; j++) acc[i][j] = (f32x4){0.f, 0.f, 0.f, 0.f};

    const int sr = tid >> 4;    // staging row 0..15
    const int kq = tid & 15;    // staging float4 index

    for (int kt = 0; kt < 256; kt += 64) {
        // ---- stage A (fp32 -> hi/lo bf16, swizzled) ----
#pragma unroll
        for (int p = 0; p < 8; ++p) {
            int row = p * 16 + sr;
            int gm = m0 + row; if (gm >= M) gm = M - 1;
            float4 v = *reinterpret_cast<const float4*>(A + (size_t)gm * F + kt + kq * 4);
            unsigned p0 = split_bf16(v.x);
            unsigned p1 = split_bf16(v.y);
            unsigned p2 = split_bf16(v.z);
            unsigned p3 = split_bf16(v.w);
            s16x4 h4, l4;
            h4[0] = (short)(p0 & 0xFFFFu); l4[0] = (short)(p0 >> 16);
            h4[1] = (short)(p1 & 0xFFFFu); l4[1] = (short)(p1 >> 16);
            h4[2] = (short)(p2 & 0xFFFFu); l4[2] = (short)(p2 >> 16);
            h4[3] = (short)(p3 & 0xFFFFu); l4[3] = (short)(p3 >> 16);
            int sidx = row * 64 + ((kq * 4) ^ ((row & 7) << 3));
            *reinterpret_cast<s16x4*>(&Ah[sidx]) = h4;
            *reinterpret_cast<s16x4*>(&Al[sidx]) = l4;
        }
        // ---- stage B (already bf16, swizzled) ----
#pragma unroll
        for (int p = 0; p < 4; ++p) {
            int u = p * 256 + tid;
            int n = u >> 3, slot = u & 7;
            size_t gofs = (size_t)(n0 + n) * F + kt + slot * 8;
            s16x8 hv = *reinterpret_cast<const s16x8*>(Bth + gofs);
            s16x8 lv = *reinterpret_cast<const s16x8*>(Btl + gofs);
            int sidx = n * 64 + ((slot * 8) ^ ((n & 7) << 3));
            *reinterpret_cast<s16x8*>(&Bh[sidx]) = hv;
            *reinterpret_cast<s16x8*>(&Bl[sidx]) = lv;
        }
        __syncthreads();
        // ---- compute: 2 k-substeps of 32 ----
#pragma unroll
        for (int ks = 0; ks < 2; ++ks) {
            int kk = ks * 32 + kgrp * 8;
            s16x8 ah[4], al[4], bh[4], bl[4];
#pragma unroll
            for (int i = 0; i < 4; ++i) {
                int row = wm * 64 + i * 16 + lrow;
                int ia = row * 64 + (kk ^ ((row & 7) << 3));
                ah[i] = *reinterpret_cast<const s16x8*>(&Ah[ia]);
                al[i] = *reinterpret_cast<const s16x8*>(&Al[ia]);
                int col = wn * 64 + i * 16 + lrow;
                int ib = col * 64 + (kk ^ ((col & 7) << 3));
                bh[i] = *reinterpret_cast<const s16x8*>(&Bh[ib]);
                bl[i] = *reinterpret_cast<const s16x8*>(&Bl[ib]);
            }
#pragma unroll
            for (int i = 0; i < 4; ++i)
#pragma unroll
                for (int j = 0; j < 4; ++j) {
                    acc[i][j] = __builtin_amdgcn_mfma_f32_16x16x32_bf16(ah[i], bh[j], acc[i][j], 0, 0, 0);
                    acc[i][j] = __builtin_amdgcn_mfma_f32_16x16x32_bf16(ah[i], bl[j], acc[i][j], 0, 0, 0);
                    acc[i][j] = __builtin_amdgcn_mfma_f32_16x16x32_bf16(al[i], bh[j], acc[i][j], 0, 0, 0);
                }
        }
        __syncthreads();
    }

    // ---- epilogue: C row = kgrp*4 + r (lane>>4 group), col = lrow (m89-verified layout) ----
#pragma unroll
    for (int i = 0; i < 4; ++i) {
#pragma unroll
        for (int r = 0; r < 4; ++r) {
            int m = m0 + wm * 64 + i * 16 + kgrp * 4 + r;
            if (m >= M) continue;
            float dv = dis[m];
#pragma unroll
            for (int j = 0; j < 4; ++j) {
                int n = n0 + wn * 64 + j * 16 + lrow;
                G[(size_t)m * F + n] = (_Float16)(acc[i][j][r] * dv);
            }
        }
    }
}

// ---------------- CSR gather: 2 edges per wave (half-wave per row, 16B/lane) ----------------
__global__ __launch_bounds__(256) void k_aggregate_relu(
    const _Float16* __restrict__ g, const int* __restrict__ row_off,
    const int* __restrict__ csr_src, const float* __restrict__ dis,
    const float* __restrict__ b, float* __restrict__ h)
{
    int d = blockIdx.x * 4 + (threadIdx.x >> 6);
    int lane = threadIdx.x & 63;
    int hf = lane >> 5, lp = lane & 31;
    const half8* g8 = reinterpret_cast<const half8*>(g);   // 32 half8 per row
    float a[8] = {0, 0, 0, 0, 0, 0, 0, 0};
    float a2[8] = {0, 0, 0, 0, 0, 0, 0, 0};
    if (hf == 0) {
        half8 sv = g8[(size_t)d * 32 + lp];
#pragma unroll
        for (int k = 0; k < 8; k++) a[k] = (float)sv[k];
    }
    int j0 = row_off[d], j1 = row_off[d + 1];
    int j = j0 + hf;
    for (; j + 2 < j1; j += 4) {
        int s0 = csr_src[j], s1 = csr_src[j + 2];
        half8 v0 = g8[(size_t)s0 * 32 + lp];
        half8 v1 = g8[(size_t)s1 * 32 + lp];
#pragma unroll
        for (int k = 0; k < 8; k++) { a[k] += (float)v0[k]; a2[k] += (float)v1[k]; }
    }
    if (j < j1) {
        int s0 = csr_src[j];
        half8 v0 = g8[(size_t)s0 * 32 + lp];
#pragma unroll
        for (int k = 0; k < 8; k++) a[k] += (float)v0[k];
    }
#pragma unroll
    for (int k = 0; k < 8; k++) {
        a[k] += a2[k];
        a[k] += __shfl_xor(a[k], 32);
    }
    float sc = dis[d];
    int c = lp * 8 + hf * 4;
    float4 bb = *reinterpret_cast<const float4*>(b + c);
    float4 o;
    o.x = fmaxf(fmaf(sc, a[hf * 4 + 0], bb.x), 0.0f);
    o.y = fmaxf(fmaf(sc, a[hf * 4 + 1], bb.y), 0.0f);
    o.z = fmaxf(fmaf(sc, a[hf * 4 + 2], bb.z), 0.0f);
    o.w = fmaxf(fmaf(sc, a[hf * 4 + 3], bb.w), 0.0f);
    *reinterpret_cast<float4*>(h + (size_t)d * F + c) = o;
}

__global__ __launch_bounds__(256) void k_aggregate_out(
    const _Float16* __restrict__ g, const int* __restrict__ row_off,
    const int* __restrict__ csr_src, const float* __restrict__ dis,
    const float* __restrict__ bmu, const float* __restrict__ blv,
    float* __restrict__ out)
{
    int d = blockIdx.x * 4 + (threadIdx.x >> 6);
    int lane = threadIdx.x & 63;
    int hf = lane >> 5, lp = lane & 31;
    const half8* g8 = reinterpret_cast<const half8*>(g);
    float a[8] = {0, 0, 0, 0, 0, 0, 0, 0};
    float a2[8] = {0, 0, 0, 0, 0, 0, 0, 0};
    if (hf == 0) {
        half8 sv = g8[(size_t)d * 32 + lp];
#pragma unroll
        for (int k = 0; k < 8; k++) a[k] = (float)sv[k];
    }
    int j0 = row_off[d], j1 = row_off[d + 1];
    int j = j0 + hf;
    for (; j + 2 < j1; j += 4) {
        int s0 = csr_src[j], s1 = csr_src[j + 2];
        half8 v0 = g8[(size_t)s0 * 32 + lp];
        half8 v1 = g8[(size_t)s1 * 32 + lp];
#pragma unroll
        for (int k = 0; k < 8; k++) { a[k] += (float)v0[k]; a2[k] += (float)v1[k]; }
    }
    if (j < j1) {
        int s0 = csr_src[j];
        half8 v0 = g8[(size_t)s0 * 32 + lp];
#pragma unroll
        for (int k = 0; k < 8; k++) a[k] += (float)v0[k];
    }
#pragma unroll
    for (int k = 0; k < 8; k++) {
        a[k] += a2[k];
        a[k] += __shfl_xor(a[k], 32);
    }
    float sc = dis[d];
    int ch = lp * 8 + hf * 4;                 // 0..252
    float va = a[hf * 4 + 0], vb = a[hf * 4 + 1], vc = a[hf * 4 + 2], vd = a[hf * 4 + 3];
    if (ch < 128) {
        float4 bb = *reinterpret_cast<const float4*>(bmu + ch);
        float4 o = make_float4(fmaf(sc, va, bb.x), fmaf(sc, vb, bb.y),
                               fmaf(sc, vc, bb.z), fmaf(sc, vd, bb.w));
        *reinterpret_cast<float4*>(out + (size_t)d * 128 + ch) = o;
    } else {
        int c2 = ch - 128;
        float4 bb = *reinterpret_cast<const float4*>(blv + c2);
        float4 o = make_float4(fmaf(sc, va, bb.x), fmaf(sc, vb, bb.y),
                               fmaf(sc, vc, bb.z), fmaf(sc, vd, bb.w));
        *reinterpret_cast<float4*>(out + LV_OFF + (size_t)d * 128 + c2) = o;
    }
}

extern "C" void kernel_launch(void* const* d_in, const int* in_sizes, int n_in,
                              void* d_out, int out_size, void* d_ws, size_t ws_size,
                              hipStream_t stream) {
    const float* x   = (const float*)d_in[0];
    const int*   ei  = (const int*)d_in[1];
    const int*   src = ei;
    const int*   dst = ei + E_EDGES;
    const float* W1  = (const float*)d_in[2];
    const float* b1  = (const float*)d_in[3];
    const float* Wmu = (const float*)d_in[4];
    const float* bmu = (const float*)d_in[5];
    const float* Wlv = (const float*)d_in[6];
    const float* blv = (const float*)d_in[7];
    float* out = (float*)d_out;

    // workspace carve-up (1 KiB aligned)
    char* ws = (char*)d_ws;
    size_t o = 0;
    auto carve = [&](size_t bytes) -> char* {
        char* p = ws + o;
        o = (o + bytes + 1023) & ~(size_t)1023;
        return p;
    };
    float*    dis     = (float*)   carve(400000);
    int*      cnt     = (int*)     carve(400000);
    int*      row_off = (int*)     carve(400004);
    int*      cursor  = (int*)     carve(400000);
    int*      bsum    = (int*)     carve(SCAN_BLK * 4);
    short*    Wt1h    = (short*)   carve(131072);
    short*    Wt1l    = (short*)   carve(131072);
    short*    Wtch    = (short*)   carve(131072);
    short*    Wtcl    = (short*)   carve(131072);
    int*      csr_src = (int*)     carve((size_t)E_EDGES * 4);       // 6.4 MB
    _Float16* g       = (_Float16*)carve((size_t)N_NODES * F * 2);   // 51.2 MB
    (void)ws_size;

    // ---- graph preprocessing (shared by both aggregations) ----
    k_zero <<<(N_NODES + 255) / 256, 256, 0, stream>>>(cnt, N_NODES);
    k_count<<<(E_EDGES + 255) / 256, 256, 0, stream>>>(dst, cnt);
    k_dis  <<<(N_NODES + 255) / 256, 256, 0, stream>>>(cnt, dis);
    k_scan1<<<SCAN_BLK, 256, 0, stream>>>(cnt, row_off, bsum);
    k_scan2<<<1, 64, 0, stream>>>(bsum);
    k_scan3<<<SCAN_BLK, 256, 0, stream>>>(row_off, bsum, cursor);
    k_fill <<<(E_EDGES + 255) / 256, 256, 0, stream>>>(src, dst, cursor, csr_src);
    k_wprep<<<256, 256, 0, stream>>>(W1, Wmu, Wlv, Wt1h, Wt1l, Wtch, Wtcl);

    dim3 gemm_grid(782, 2);   // ceil(100000/128) x 256/128

    // layer 1: g = fp16((x@W1)*dis) ; h = relu(dis*(g[self]+sum g[nbr]) + b1) -> d_out (temp)
    k_gemm_mfma     <<<gemm_grid, 256, 0, stream>>>(x, Wt1h, Wt1l, dis, g, N_NODES);
    k_aggregate_relu<<<N_NODES / 4, 256, 0, stream>>>(g, row_off, csr_src, dis, b1, out);

    // layer 2 (mu|lv fused): g = fp16((h@Wcat)*dis) ; out = dis*(g[self]+sum g[nbr]) + b
    k_gemm_mfma     <<<gemm_grid, 256, 0, stream>>>(out, Wtch, Wtcl, dis, g, N_NODES);
    k_aggregate_out <<<N_NODES / 4, 256, 0, stream>>>(g, row_off, csr_src, dis, bmu, blv, out);
}

// Round 6
// 515.611 us; speedup vs baseline: 21.5836x; 1.3007x over previous
//
#include <hip/hip_runtime.h>
#include <hip/hip_fp16.h>

#define N_NODES 100000
#define E_EDGES 1600000
#define F 256              // feature width at every stage
#define LV_OFF 12800000    // 100000*128
#define SCAN_BLK 98        // ceil(100000/1024)
#define GEMM_BLKS 1564     // ceil(100000/128) * 2
#define FILL_BLKS 6250     // ceil(1.6M/256)

typedef _Float16 half8 __attribute__((ext_vector_type(8)));
typedef _Float16 f16x4 __attribute__((ext_vector_type(4)));
typedef float    f32x4 __attribute__((ext_vector_type(4)));

// ---------------- small prep kernels ----------------
__global__ void k_zero(int* __restrict__ p, int n) {
    int i = blockIdx.x * 256 + threadIdx.x;
    if (i < n) p[i] = 0;
}

__global__ void k_count(const int* __restrict__ dst, int* __restrict__ cnt) {
    int e = blockIdx.x * 256 + threadIdx.x;
    if (e < E_EDGES) atomicAdd(&cnt[dst[e]], 1);
}

__global__ void k_dis(const int* __restrict__ cnt, float* __restrict__ dis) {
    int i = blockIdx.x * 256 + threadIdx.x;
    if (i < N_NODES) dis[i] = rsqrtf((float)cnt[i] + 1.0f);
}

__global__ __launch_bounds__(256) void k_scan1(const int* __restrict__ cnt,
                                               int* __restrict__ row_off,
                                               int* __restrict__ bsum) {
    __shared__ int sd[256];
    int tid = threadIdx.x;
    int base = blockIdx.x * 1024 + tid * 4;
    int c[4]; int s = 0;
#pragma unroll
    for (int k = 0; k < 4; k++) {
        int i = base + k;
        c[k] = (i < N_NODES) ? cnt[i] : 0;
        s += c[k];
    }
    sd[tid] = s;
    __syncthreads();
    for (int off = 1; off < 256; off <<= 1) {
        int t = (tid >= off) ? sd[tid - off] : 0;
        __syncthreads();
        sd[tid] += t;
        __syncthreads();
    }
    int run = sd[tid] - s;
#pragma unroll
    for (int k = 0; k < 4; k++) {
        int i = base + k;
        if (i < N_NODES) row_off[i] = run;
        run += c[k];
    }
    if (tid == 255) bsum[blockIdx.x] = sd[255];
}

__global__ void k_scan2(int* __restrict__ bsum) {
    if (threadIdx.x == 0 && blockIdx.x == 0) {
        int run = 0;
        for (int i = 0; i < SCAN_BLK; ++i) { int t = bsum[i]; bsum[i] = run; run += t; }
    }
}

__global__ __launch_bounds__(256) void k_scan3(int* __restrict__ row_off,
                                               const int* __restrict__ bsum,
                                               int* __restrict__ cursor) {
    int tid = threadIdx.x;
    int add = bsum[blockIdx.x];
    int base = blockIdx.x * 1024 + tid * 4;
#pragma unroll
    for (int k = 0; k < 4; k++) {
        int i = base + k;
        if (i < N_NODES) {
            int v = row_off[i] + add;
            row_off[i] = v;
            cursor[i] = v;
        }
    }
    if (blockIdx.x == 0 && tid == 0) row_off[N_NODES] = E_EDGES;
}

// build transposed fp16 weights: Wt1[n][k] from W1[k][n]; Wtc[n][k] from Wmu|Wlv
__global__ void k_wprep(const float* __restrict__ W1,
                        const float* __restrict__ Wmu, const float* __restrict__ Wlv,
                        _Float16* __restrict__ Wt1, _Float16* __restrict__ Wtc) {
    int idx = blockIdx.x * 256 + threadIdx.x;   // 65536
    int n = idx >> 8, k = idx & 255;
    Wt1[n * 256 + k] = (_Float16)W1[k * 256 + n];
    float wc = (n < 128) ? Wmu[k * 128 + n] : Wlv[k * 128 + (n - 128)];
    Wtc[n * 256 + k] = (_Float16)wc;
}

// ---------------- fp16 MFMA GEMM tile body ----------------
// A fp32 [M,256] row-major; Bt fp16 [256n][256k] (transposed); G fp16 [M,256].
__device__ __forceinline__ void gemm_tile(
    const float* __restrict__ A, const _Float16* __restrict__ Bt,
    const float* __restrict__ dis, _Float16* __restrict__ G, int M,
    int m0, int n0, int tid, _Float16* Ah, _Float16* Bh)
{
    const int wave = tid >> 6, lane = tid & 63;
    const int wm   = wave & 1, wn = wave >> 1;
    const int lrow = lane & 15, kgrp = lane >> 4;

    f32x4 acc[4][4];
#pragma unroll
    for (int i = 0; i < 4; i++)
#pragma unroll
        for (int j = 0; j < 4; j++) acc[i][j] = (f32x4){0.f, 0.f, 0.f, 0.f};

    const int sr = tid >> 4;    // staging row 0..15
    const int kq = tid & 15;    // staging float4 index

    for (int kt = 0; kt < 256; kt += 64) {
        // ---- stage A (fp32 -> fp16, swizzled) ----
#pragma unroll
        for (int p = 0; p < 8; ++p) {
            int row = p * 16 + sr;
            int gm = m0 + row; if (gm >= M) gm = M - 1;
            float4 v = *reinterpret_cast<const float4*>(A + (size_t)gm * F + kt + kq * 4);
            f16x4 h4;
            h4[0] = (_Float16)v.x; h4[1] = (_Float16)v.y;
            h4[2] = (_Float16)v.z; h4[3] = (_Float16)v.w;
            int sidx = row * 64 + ((kq * 4) ^ ((row & 7) << 3));
            *reinterpret_cast<f16x4*>(&Ah[sidx]) = h4;
        }
        // ---- stage B (already fp16, swizzled) ----
#pragma unroll
        for (int p = 0; p < 4; ++p) {
            int u = p * 256 + tid;
            int n = u >> 3, slot = u & 7;
            half8 hv = *reinterpret_cast<const half8*>(Bt + (size_t)(n0 + n) * F + kt + slot * 8);
            int sidx = n * 64 + ((slot * 8) ^ ((n & 7) << 3));
            *reinterpret_cast<half8*>(&Bh[sidx]) = hv;
        }
        __syncthreads();
        // ---- compute: 2 k-substeps of 32 ----
#pragma unroll
        for (int ks = 0; ks < 2; ++ks) {
            int kk = ks * 32 + kgrp * 8;
            half8 ah[4], bh[4];
#pragma unroll
            for (int i = 0; i < 4; ++i) {
                int row = wm * 64 + i * 16 + lrow;
                ah[i] = *reinterpret_cast<const half8*>(&Ah[row * 64 + (kk ^ ((row & 7) << 3))]);
                int col = wn * 64 + i * 16 + lrow;
                bh[i] = *reinterpret_cast<const half8*>(&Bh[col * 64 + (kk ^ ((col & 7) << 3))]);
            }
#pragma unroll
            for (int i = 0; i < 4; ++i)
#pragma unroll
                for (int j = 0; j < 4; ++j)
                    acc[i][j] = __builtin_amdgcn_mfma_f32_16x16x32_f16(ah[i], bh[j], acc[i][j], 0, 0, 0);
        }
        __syncthreads();
    }

    // ---- epilogue: C row = kgrp*4 + r, col = lrow (m89-verified layout) ----
#pragma unroll
    for (int i = 0; i < 4; ++i) {
#pragma unroll
        for (int r = 0; r < 4; ++r) {
            int m = m0 + wm * 64 + i * 16 + kgrp * 4 + r;
            if (m >= M) continue;
            float dv = dis[m];
#pragma unroll
            for (int j = 0; j < 4; ++j) {
                int n = n0 + wn * 64 + j * 16 + lrow;
                G[(size_t)m * F + n] = (_Float16)(acc[i][j][r] * dv);
            }
        }
    }
}

// ---------------- fused: GEMM-1 tiles + CSR fill (independent work, co-scheduled) ----------------
// grid = 5*GEMM_BLKS; bid%5==0 -> gemm tile bid/5; else fill chunk.
__global__ __launch_bounds__(256) void k_gemm_fill(
    const float* __restrict__ A, const _Float16* __restrict__ Bt,
    const float* __restrict__ dis, _Float16* __restrict__ G, int M,
    const int* __restrict__ src, const int* __restrict__ dst,
    int* __restrict__ cursor, int* __restrict__ csr_src)
{
    __shared__ _Float16 Ah[128 * 64];
    __shared__ _Float16 Bh[128 * 64];
    int bid = blockIdx.x;
    int r5 = bid % 5;
    if (r5 == 0) {
        int gid = bid / 5;   // 0..1563
        gemm_tile(A, Bt, dis, G, M, (gid >> 1) * 128, (gid & 1) * 128, threadIdx.x, Ah, Bh);
    } else {
        int fid = (bid / 5) * 4 + r5 - 1;
        int e = fid * 256 + threadIdx.x;
        if (e < E_EDGES) {
            int pos = atomicAdd(&cursor[dst[e]], 1);
            csr_src[pos] = src[e];
        }
    }
}

// ---------------- standalone fp16 GEMM (layer 2) ----------------
__global__ __launch_bounds__(256) void k_gemm_f16(
    const float* __restrict__ A, const _Float16* __restrict__ Bt,
    const float* __restrict__ dis, _Float16* __restrict__ G, int M)
{
    __shared__ _Float16 Ah[128 * 64];
    __shared__ _Float16 Bh[128 * 64];
    gemm_tile(A, Bt, dis, G, M, blockIdx.x * 128, blockIdx.y * 128, threadIdx.x, Ah, Bh);
}

// ---------------- CSR gather: half-wave per row, 4 rows in flight ----------------
__global__ __launch_bounds__(256) void k_aggregate_relu(
    const _Float16* __restrict__ g, const int* __restrict__ row_off,
    const int* __restrict__ csr_src, const float* __restrict__ dis,
    const float* __restrict__ b, float* __restrict__ h)
{
    int d = blockIdx.x * 4 + (threadIdx.x >> 6);
    int lane = threadIdx.x & 63;
    int hf = lane >> 5, lp = lane & 31;
    const half8* g8 = reinterpret_cast<const half8*>(g);   // 32 half8 per row
    float a[8] = {0,0,0,0,0,0,0,0}, a2[8] = {0,0,0,0,0,0,0,0};
    float a3[8] = {0,0,0,0,0,0,0,0}, a4[8] = {0,0,0,0,0,0,0,0};
    if (hf == 0) {
        half8 sv = g8[(size_t)d * 32 + lp];
#pragma unroll
        for (int k = 0; k < 8; k++) a[k] = (float)sv[k];
    }
    int j0 = row_off[d], j1 = row_off[d + 1];
    int j = j0 + hf;
    for (; j + 6 < j1; j += 8) {
        int s0 = csr_src[j], s1 = csr_src[j + 2], s2 = csr_src[j + 4], s3 = csr_src[j + 6];
        half8 v0 = g8[(size_t)s0 * 32 + lp];
        half8 v1 = g8[(size_t)s1 * 32 + lp];
        half8 v2 = g8[(size_t)s2 * 32 + lp];
        half8 v3 = g8[(size_t)s3 * 32 + lp];
#pragma unroll
        for (int k = 0; k < 8; k++) {
            a[k] += (float)v0[k]; a2[k] += (float)v1[k];
            a3[k] += (float)v2[k]; a4[k] += (float)v3[k];
        }
    }
    for (; j < j1; j += 2) {
        int s0 = csr_src[j];
        half8 v0 = g8[(size_t)s0 * 32 + lp];
#pragma unroll
        for (int k = 0; k < 8; k++) a[k] += (float)v0[k];
    }
#pragma unroll
    for (int k = 0; k < 8; k++) {
        a[k] += a2[k] + a3[k] + a4[k];
        a[k] += __shfl_xor(a[k], 32);
    }
    float sc = dis[d];
    int c = lp * 8 + hf * 4;
    float4 bb = *reinterpret_cast<const float4*>(b + c);
    float4 o;
    o.x = fmaxf(fmaf(sc, a[hf * 4 + 0], bb.x), 0.0f);
    o.y = fmaxf(fmaf(sc, a[hf * 4 + 1], bb.y), 0.0f);
    o.z = fmaxf(fmaf(sc, a[hf * 4 + 2], bb.z), 0.0f);
    o.w = fmaxf(fmaf(sc, a[hf * 4 + 3], bb.w), 0.0f);
    *reinterpret_cast<float4*>(h + (size_t)d * F + c) = o;
}

__global__ __launch_bounds__(256) void k_aggregate_out(
    const _Float16* __restrict__ g, const int* __restrict__ row_off,
    const int* __restrict__ csr_src, const float* __restrict__ dis,
    const float* __restrict__ bmu, const float* __restrict__ blv,
    float* __restrict__ out)
{
    int d = blockIdx.x * 4 + (threadIdx.x >> 6);
    int lane = threadIdx.x & 63;
    int hf = lane >> 5, lp = lane & 31;
    const half8* g8 = reinterpret_cast<const half8*>(g);
    float a[8] = {0,0,0,0,0,0,0,0}, a2[8] = {0,0,0,0,0,0,0,0};
    float a3[8] = {0,0,0,0,0,0,0,0}, a4[8] = {0,0,0,0,0,0,0,0};
    if (hf == 0) {
        half8 sv = g8[(size_t)d * 32 + lp];
#pragma unroll
        for (int k = 0; k < 8; k++) a[k] = (float)sv[k];
    }
    int j0 = row_off[d], j1 = row_off[d + 1];
    int j = j0 + hf;
    for (; j + 6 < j1; j += 8) {
        int s0 = csr_src[j], s1 = csr_src[j + 2], s2 = csr_src[j + 4], s3 = csr_src[j + 6];
        half8 v0 = g8[(size_t)s0 * 32 + lp];
        half8 v1 = g8[(size_t)s1 * 32 + lp];
        half8 v2 = g8[(size_t)s2 * 32 + lp];
        half8 v3 = g8[(size_t)s3 * 32 + lp];
#pragma unroll
        for (int k = 0; k < 8; k++) {
            a[k] += (float)v0[k]; a2[k] += (float)v1[k];
            a3[k] += (float)v2[k]; a4[k] += (float)v3[k];
        }
    }
    for (; j < j1; j += 2) {
        int s0 = csr_src[j];
        half8 v0 = g8[(size_t)s0 * 32 + lp];
#pragma unroll
        for (int k = 0; k < 8; k++) a[k] += (float)v0[k];
    }
#pragma unroll
    for (int k = 0; k < 8; k++) {
        a[k] += a2[k] + a3[k] + a4[k];
        a[k] += __shfl_xor(a[k], 32);
    }
    float sc = dis[d];
    int ch = lp * 8 + hf * 4;                 // 0..252
    float va = a[hf * 4 + 0], vb = a[hf * 4 + 1], vc = a[hf * 4 + 2], vd = a[hf * 4 + 3];
    if (ch < 128) {
        float4 bb = *reinterpret_cast<const float4*>(bmu + ch);
        float4 o = make_float4(fmaf(sc, va, bb.x), fmaf(sc, vb, bb.y),
                               fmaf(sc, vc, bb.z), fmaf(sc, vd, bb.w));
        *reinterpret_cast<float4*>(out + (size_t)d * 128 + ch) = o;
    } else {
        int c2 = ch - 128;
        float4 bb = *reinterpret_cast<const float4*>(blv + c2);
        float4 o = make_float4(fmaf(sc, va, bb.x), fmaf(sc, vb, bb.y),
                               fmaf(sc, vc, bb.z), fmaf(sc, vd, bb.w));
        *reinterpret_cast<float4*>(out + LV_OFF + (size_t)d * 128 + c2) = o;
    }
}

extern "C" void kernel_launch(void* const* d_in, const int* in_sizes, int n_in,
                              void* d_out, int out_size, void* d_ws, size_t ws_size,
                              hipStream_t stream) {
    const float* x   = (const float*)d_in[0];
    const int*   ei  = (const int*)d_in[1];
    const int*   src = ei;
    const int*   dst = ei + E_EDGES;
    const float* W1  = (const float*)d_in[2];
    const float* b1  = (const float*)d_in[3];
    const float* Wmu = (const float*)d_in[4];
    const float* bmu = (const float*)d_in[5];
    const float* Wlv = (const float*)d_in[6];
    const float* blv = (const float*)d_in[7];
    float* out = (float*)d_out;

    // workspace carve-up (1 KiB aligned)
    char* ws = (char*)d_ws;
    size_t o = 0;
    auto carve = [&](size_t bytes) -> char* {
        char* p = ws + o;
        o = (o + bytes + 1023) & ~(size_t)1023;
        return p;
    };
    float*    dis     = (float*)   carve(400000);
    int*      cnt     = (int*)     carve(400000);
    int*      row_off = (int*)     carve(400004);
    int*      cursor  = (int*)     carve(400000);
    int*      bsum    = (int*)     carve(SCAN_BLK * 4);
    _Float16* Wt1     = (_Float16*)carve(131072);
    _Float16* Wtc     = (_Float16*)carve(131072);
    int*      csr_src = (int*)     carve((size_t)E_EDGES * 4);       // 6.4 MB
    _Float16* g       = (_Float16*)carve((size_t)N_NODES * F * 2);   // 51.2 MB
    (void)ws_size;

    // ---- graph preprocessing (shared by both aggregations) ----
    k_zero <<<(N_NODES + 255) / 256, 256, 0, stream>>>(cnt, N_NODES);
    k_count<<<(E_EDGES + 255) / 256, 256, 0, stream>>>(dst, cnt);
    k_dis  <<<(N_NODES + 255) / 256, 256, 0, stream>>>(cnt, dis);
    k_scan1<<<SCAN_BLK, 256, 0, stream>>>(cnt, row_off, bsum);
    k_scan2<<<1, 64, 0, stream>>>(bsum);
    k_scan3<<<SCAN_BLK, 256, 0, stream>>>(row_off, bsum, cursor);
    k_wprep<<<256, 256, 0, stream>>>(W1, Wmu, Wlv, Wt1, Wtc);

    // layer 1 GEMM fused with CSR fill (independent; co-scheduled on the CUs)
    k_gemm_fill<<<5 * GEMM_BLKS, 256, 0, stream>>>(x, Wt1, dis, g, N_NODES,
                                                   src, dst, cursor, csr_src);
    k_aggregate_relu<<<N_NODES / 4, 256, 0, stream>>>(g, row_off, csr_src, dis, b1, out);

    // layer 2 (mu|lv fused): g = fp16((h@Wtc^T)*dis) ; out = dis*(g[self]+sum g[nbr]) + b
    dim3 gemm_grid(782, 2);
    k_gemm_f16<<<gemm_grid, 256, 0, stream>>>(out, Wtc, dis, g, N_NODES);
    k_aggregate_out<<<N_NODES / 4, 256, 0, stream>>>(g, row_off, csr_src, dis, bmu, blv, out);
}

// Round 7
// 419.278 us; speedup vs baseline: 26.5427x; 1.2298x over previous
//
#include <hip/hip_runtime.h>
#include <hip/hip_fp16.h>

#define N_NODES 100000
#define E_EDGES 1600000
#define F 256              // feature width at every stage
#define LV_OFF 12800000    // 100000*128
#define NBUK 782           // ceil(100000/128) dst-buckets of 128 nodes
#define EPB 8192           // edges per binning block
#define NBLK_BIN 196       // ceil(1.6M/8192)

typedef _Float16 half8 __attribute__((ext_vector_type(8)));
typedef _Float16 f16x4 __attribute__((ext_vector_type(4)));
typedef float    f32x4 __attribute__((ext_vector_type(4)));

__global__ void k_zero(int* __restrict__ p, int n) {
    int i = blockIdx.x * 256 + threadIdx.x;
    if (i < n) p[i] = 0;
}

// build transposed fp16 weights: Wt1[n][k] from W1[k][n]; Wtc[n][k] from Wmu|Wlv
__global__ void k_wprep(const float* __restrict__ W1,
                        const float* __restrict__ Wmu, const float* __restrict__ Wlv,
                        _Float16* __restrict__ Wt1, _Float16* __restrict__ Wtc) {
    int idx = blockIdx.x * 256 + threadIdx.x;   // 65536
    int n = idx >> 8, k = idx & 255;
    Wt1[n * 256 + k] = (_Float16)W1[k * 256 + n];
    float wc = (n < 128) ? Wmu[k * 128 + n] : Wlv[k * 128 + (n - 128)];
    Wtc[n * 256 + k] = (_Float16)wc;
}

// ---------------- binning pass A: per-block bucket histogram + chunk reservation ----------------
__global__ __launch_bounds__(256) void k_binA(const int* __restrict__ dst,
                                              int* __restrict__ gcnt, int* __restrict__ cbase) {
    __shared__ int h[NBUK];
    int blk = blockIdx.x, tid = threadIdx.x;
    for (int b = tid; b < NBUK; b += 256) h[b] = 0;
    __syncthreads();
    int e0 = blk * EPB, e1 = min(e0 + EPB, E_EDGES);
    for (int e = e0 + tid; e < e1; e += 256) atomicAdd(&h[dst[e] >> 7], 1);
    __syncthreads();
    for (int b = tid; b < NBUK; b += 256) {
        int c = h[b];
        cbase[blk * NBUK + b] = c ? atomicAdd(&gcnt[b], c) : 0;
    }
}

// ---------------- exclusive scan of 782 bucket counts ----------------
__global__ __launch_bounds__(1024) void k_scan782(const int* __restrict__ gcnt,
                                                  int* __restrict__ gbase) {
    __shared__ int sd[1024];
    int tid = threadIdx.x;
    int v = (tid < NBUK) ? gcnt[tid] : 0;
    sd[tid] = v;
    __syncthreads();
    for (int off = 1; off < 1024; off <<= 1) {
        int t = (tid >= off) ? sd[tid - off] : 0;
        __syncthreads();
        sd[tid] += t;
        __syncthreads();
    }
    if (tid < NBUK) gbase[tid] = sd[tid] - v;    // exclusive
    if (tid == NBUK - 1) gbase[NBUK] = sd[tid];  // total = E
}

// ---------------- binning pass C: place (dst,src) records into reserved chunks ----------------
__global__ __launch_bounds__(256) void k_binC(const int* __restrict__ src, const int* __restrict__ dst,
                                              const int* __restrict__ gbase, const int* __restrict__ cbase,
                                              unsigned long long* __restrict__ ebuf) {
    __shared__ int h2[NBUK];
    __shared__ int bs[NBUK];
    int blk = blockIdx.x, tid = threadIdx.x;
    for (int b = tid; b < NBUK; b += 256) {
        h2[b] = 0;
        bs[b] = gbase[b] + cbase[blk * NBUK + b];
    }
    __syncthreads();
    int e0 = blk * EPB, e1 = min(e0 + EPB, E_EDGES);
    for (int e = e0 + tid; e < e1; e += 256) {
        int d = dst[e];
        int b = d >> 7;
        int lr = atomicAdd(&h2[b], 1);
        ebuf[bs[b] + lr] = ((unsigned long long)(unsigned)d << 32) | (unsigned)src[e];
    }
}

// ---------------- binning pass D: per-bucket group-by-dst -> csr_src, row_off, dis ----------------
__global__ __launch_bounds__(256) void k_binD(const unsigned long long* __restrict__ ebuf,
                                              const int* __restrict__ gbase,
                                              int* __restrict__ csr_src, int* __restrict__ row_off,
                                              float* __restrict__ dis) {
    __shared__ int dh[128], dsc[128], dcur[128];
    int b = blockIdx.x, tid = threadIdx.x;
    if (tid < 128) dh[tid] = 0;
    __syncthreads();
    int s0 = gbase[b], s1 = gbase[b + 1];
    for (int i = s0 + tid; i < s1; i += 256)
        atomicAdd(&dh[(int)(ebuf[i] >> 32) & 127], 1);
    __syncthreads();
    if (tid < 128) dsc[tid] = dh[tid];
    __syncthreads();
    for (int off = 1; off < 128; off <<= 1) {
        int t = 0;
        if (tid < 128 && tid >= off) t = dsc[tid - off];
        __syncthreads();
        if (tid < 128) dsc[tid] += t;
        __syncthreads();
    }
    if (tid < 128) {
        int ex = dsc[tid] - dh[tid];   // exclusive within bucket
        dcur[tid] = ex;
        int node = b * 128 + tid;
        if (node < N_NODES) {
            row_off[node] = s0 + ex;
            dis[node] = rsqrtf((float)dh[tid] + 1.0f);
        }
    }
    if (b == 0 && tid == 128) row_off[N_NODES] = E_EDGES;
    __syncthreads();
    for (int i = s0 + tid; i < s1; i += 256) {
        unsigned long long ed = ebuf[i];
        int dl = (int)(ed >> 32) & 127;
        int lr = atomicAdd(&dcur[dl], 1);
        csr_src[s0 + lr] = (int)(ed & 0xFFFFFFFFull);
    }
}

// ---------------- fp16 MFMA GEMM, 128m x 256n tile, epilogue *dis[m], fp16 out ----------------
// A [M,256] row-major (fp32 or fp16); Bt fp16 [256n][256k] transposed; G fp16 [M,256].
template <typename TA>
__global__ __launch_bounds__(256, 2) void k_gemm(
    const TA* __restrict__ A, const _Float16* __restrict__ Bt,
    const float* __restrict__ dis, _Float16* __restrict__ G, int M)
{
    __shared__ _Float16 Ah[128 * 64];   // [row][k] swizzled, 16KB
    __shared__ _Float16 Bh[256 * 64];   // [col][k] swizzled, 32KB

    const int tid  = threadIdx.x;
    const int m0   = blockIdx.x * 128;
    const int wave = tid >> 6, lane = tid & 63;
    const int wm   = wave & 1, wn = wave >> 1;      // 64-row half, 128-col half
    const int lrow = lane & 15, kgrp = lane >> 4;

    f32x4 acc[4][8];
#pragma unroll
    for (int i = 0; i < 4; i++)
#pragma unroll
        for (int j = 0; j < 8; j++) acc[i][j] = (f32x4){0.f, 0.f, 0.f, 0.f};

    for (int kt = 0; kt < 256; kt += 64) {
        // ---- stage A ----
        if constexpr (sizeof(TA) == 4) {
            const int sr = tid >> 4, kq = tid & 15;
#pragma unroll
            for (int p = 0; p < 8; ++p) {
                int row = p * 16 + sr;
                int gm = m0 + row; if (gm >= M) gm = M - 1;
                float4 v = *reinterpret_cast<const float4*>((const float*)A + (size_t)gm * F + kt + kq * 4);
                f16x4 h4;
                h4[0] = (_Float16)v.x; h4[1] = (_Float16)v.y;
                h4[2] = (_Float16)v.z; h4[3] = (_Float16)v.w;
                *reinterpret_cast<f16x4*>(&Ah[row * 64 + ((kq * 4) ^ ((row & 7) << 3))]) = h4;
            }
        } else {
#pragma unroll
            for (int p = 0; p < 4; ++p) {
                int u = p * 256 + tid;
                int row = u >> 3, slot = u & 7;
                int gm = m0 + row; if (gm >= M) gm = M - 1;
                half8 v = *reinterpret_cast<const half8*>((const _Float16*)A + (size_t)gm * F + kt + slot * 8);
                *reinterpret_cast<half8*>(&Ah[row * 64 + ((slot * 8) ^ ((row & 7) << 3))]) = v;
            }
        }
        // ---- stage B (full 256 cols) ----
#pragma unroll
        for (int p = 0; p < 8; ++p) {
            int u = p * 256 + tid;
            int n = u >> 3, slot = u & 7;
            half8 v = *reinterpret_cast<const half8*>(Bt + (size_t)n * F + kt + slot * 8);
            *reinterpret_cast<half8*>(&Bh[n * 64 + ((slot * 8) ^ ((n & 7) << 3))]) = v;
        }
        __syncthreads();
        // ---- compute: 2 k-substeps of 32 ----
#pragma unroll
        for (int ks = 0; ks < 2; ++ks) {
            int kk = ks * 32 + kgrp * 8;
            half8 ah[4], bh[8];
#pragma unroll
            for (int i = 0; i < 4; ++i) {
                int row = wm * 64 + i * 16 + lrow;
                ah[i] = *reinterpret_cast<const half8*>(&Ah[row * 64 + (kk ^ ((row & 7) << 3))]);
            }
#pragma unroll
            for (int j = 0; j < 8; ++j) {
                int col = wn * 128 + j * 16 + lrow;
                bh[j] = *reinterpret_cast<const half8*>(&Bh[col * 64 + (kk ^ ((col & 7) << 3))]);
            }
#pragma unroll
            for (int i = 0; i < 4; ++i)
#pragma unroll
                for (int j = 0; j < 8; ++j)
                    acc[i][j] = __builtin_amdgcn_mfma_f32_16x16x32_f16(ah[i], bh[j], acc[i][j], 0, 0, 0);
        }
        __syncthreads();
    }

    // ---- epilogue: C row = kgrp*4 + r, col = lrow ----
#pragma unroll
    for (int i = 0; i < 4; ++i) {
#pragma unroll
        for (int r = 0; r < 4; ++r) {
            int m = m0 + wm * 64 + i * 16 + kgrp * 4 + r;
            if (m >= M) continue;
            float dv = dis[m];
#pragma unroll
            for (int j = 0; j < 8; ++j) {
                int n = wn * 128 + j * 16 + lrow;
                G[(size_t)m * F + n] = (_Float16)(acc[i][j][r] * dv);
            }
        }
    }
}

// ---------------- CSR gather: half-wave per row, 4 rows in flight; fp16 h out ----------------
__global__ __launch_bounds__(256) void k_aggregate_relu(
    const _Float16* __restrict__ g, const int* __restrict__ row_off,
    const int* __restrict__ csr_src, const float* __restrict__ dis,
    const float* __restrict__ b, _Float16* __restrict__ h)
{
    int d = blockIdx.x * 4 + (threadIdx.x >> 6);
    int lane = threadIdx.x & 63;
    int hf = lane >> 5, lp = lane & 31;
    const half8* g8 = reinterpret_cast<const half8*>(g);   // 32 half8 per row
    float a[8] = {0,0,0,0,0,0,0,0}, a2[8] = {0,0,0,0,0,0,0,0};
    float a3[8] = {0,0,0,0,0,0,0,0}, a4[8] = {0,0,0,0,0,0,0,0};
    if (hf == 0) {
        half8 sv = g8[(size_t)d * 32 + lp];
#pragma unroll
        for (int k = 0; k < 8; k++) a[k] = (float)sv[k];
    }
    int j0 = row_off[d], j1 = row_off[d + 1];
    int j = j0 + hf;
    for (; j + 6 < j1; j += 8) {
        int s0 = csr_src[j], s1 = csr_src[j + 2], s2 = csr_src[j + 4], s3 = csr_src[j + 6];
        half8 v0 = g8[(size_t)s0 * 32 + lp];
        half8 v1 = g8[(size_t)s1 * 32 + lp];
        half8 v2 = g8[(size_t)s2 * 32 + lp];
        half8 v3 = g8[(size_t)s3 * 32 + lp];
#pragma unroll
        for (int k = 0; k < 8; k++) {
            a[k] += (float)v0[k]; a2[k] += (float)v1[k];
            a3[k] += (float)v2[k]; a4[k] += (float)v3[k];
        }
    }
    for (; j < j1; j += 2) {
        int s0 = csr_src[j];
        half8 v0 = g8[(size_t)s0 * 32 + lp];
#pragma unroll
        for (int k = 0; k < 8; k++) a[k] += (float)v0[k];
    }
#pragma unroll
    for (int k = 0; k < 8; k++) {
        a[k] += a2[k] + a3[k] + a4[k];
        a[k] += __shfl_xor(a[k], 32);
    }
    float sc = dis[d];
    int c = lp * 8 + hf * 4;
    float4 bb = *reinterpret_cast<const float4*>(b + c);
    f16x4 o;
    o[0] = (_Float16)fmaxf(fmaf(sc, a[hf * 4 + 0], bb.x), 0.0f);
    o[1] = (_Float16)fmaxf(fmaf(sc, a[hf * 4 + 1], bb.y), 0.0f);
    o[2] = (_Float16)fmaxf(fmaf(sc, a[hf * 4 + 2], bb.z), 0.0f);
    o[3] = (_Float16)fmaxf(fmaf(sc, a[hf * 4 + 3], bb.w), 0.0f);
    *reinterpret_cast<f16x4*>(h + (size_t)d * F + c) = o;
}

__global__ __launch_bounds__(256) void k_aggregate_out(
    const _Float16* __restrict__ g, const int* __restrict__ row_off,
    const int* __restrict__ csr_src, const float* __restrict__ dis,
    const float* __restrict__ bmu, const float* __restrict__ blv,
    float* __restrict__ out)
{
    int d = blockIdx.x * 4 + (threadIdx.x >> 6);
    int lane = threadIdx.x & 63;
    int hf = lane >> 5, lp = lane & 31;
    const half8* g8 = reinterpret_cast<const half8*>(g);
    float a[8] = {0,0,0,0,0,0,0,0}, a2[8] = {0,0,0,0,0,0,0,0};
    float a3[8] = {0,0,0,0,0,0,0,0}, a4[8] = {0,0,0,0,0,0,0,0};
    if (hf == 0) {
        half8 sv = g8[(size_t)d * 32 + lp];
#pragma unroll
        for (int k = 0; k < 8; k++) a[k] = (float)sv[k];
    }
    int j0 = row_off[d], j1 = row_off[d + 1];
    int j = j0 + hf;
    for (; j + 6 < j1; j += 8) {
        int s0 = csr_src[j], s1 = csr_src[j + 2], s2 = csr_src[j + 4], s3 = csr_src[j + 6];
        half8 v0 = g8[(size_t)s0 * 32 + lp];
        half8 v1 = g8[(size_t)s1 * 32 + lp];
        half8 v2 = g8[(size_t)s2 * 32 + lp];
        half8 v3 = g8[(size_t)s3 * 32 + lp];
#pragma unroll
        for (int k = 0; k < 8; k++) {
            a[k] += (float)v0[k]; a2[k] += (float)v1[k];
            a3[k] += (float)v2[k]; a4[k] += (float)v3[k];
        }
    }
    for (; j < j1; j += 2) {
        int s0 = csr_src[j];
        half8 v0 = g8[(size_t)s0 * 32 + lp];
#pragma unroll
        for (int k = 0; k < 8; k++) a[k] += (float)v0[k];
    }
#pragma unroll
    for (int k = 0; k < 8; k++) {
        a[k] += a2[k] + a3[k] + a4[k];
        a[k] += __shfl_xor(a[k], 32);
    }
    float sc = dis[d];
    int ch = lp * 8 + hf * 4;                 // 0..252
    float va = a[hf * 4 + 0], vb = a[hf * 4 + 1], vc = a[hf * 4 + 2], vd = a[hf * 4 + 3];
    if (ch < 128) {
        float4 bb = *reinterpret_cast<const float4*>(bmu + ch);
        float4 o = make_float4(fmaf(sc, va, bb.x), fmaf(sc, vb, bb.y),
                               fmaf(sc, vc, bb.z), fmaf(sc, vd, bb.w));
        *reinterpret_cast<float4*>(out + (size_t)d * 128 + ch) = o;
    } else {
        int c2 = ch - 128;
        float4 bb = *reinterpret_cast<const float4*>(blv + c2);
        float4 o = make_float4(fmaf(sc, va, bb.x), fmaf(sc, vb, bb.y),
                               fmaf(sc, vc, bb.z), fmaf(sc, vd, bb.w));
        *reinterpret_cast<float4*>(out + LV_OFF + (size_t)d * 128 + c2) = o;
    }
}

extern "C" void kernel_launch(void* const* d_in, const int* in_sizes, int n_in,
                              void* d_out, int out_size, void* d_ws, size_t ws_size,
                              hipStream_t stream) {
    const float* x   = (const float*)d_in[0];
    const int*   ei  = (const int*)d_in[1];
    const int*   src = ei;
    const int*   dst = ei + E_EDGES;
    const float* W1  = (const float*)d_in[2];
    const float* b1  = (const float*)d_in[3];
    const float* Wmu = (const float*)d_in[4];
    const float* bmu = (const float*)d_in[5];
    const float* Wlv = (const float*)d_in[6];
    const float* blv = (const float*)d_in[7];
    float* out = (float*)d_out;

    // workspace carve-up (1 KiB aligned)
    char* ws = (char*)d_ws;
    size_t o = 0;
    auto carve = [&](size_t bytes) -> char* {
        char* p = ws + o;
        o = (o + bytes + 1023) & ~(size_t)1023;
        return p;
    };
    float*    dis     = (float*)   carve(400000);
    int*      row_off = (int*)     carve(400004);
    int*      gcnt    = (int*)     carve(NBUK * 4);
    int*      gbase   = (int*)     carve((NBUK + 1) * 4);
    int*      cbase   = (int*)     carve((size_t)NBLK_BIN * NBUK * 4);   // 613 KB
    _Float16* Wt1     = (_Float16*)carve(131072);
    _Float16* Wtc     = (_Float16*)carve(131072);
    int*      csr_src = (int*)     carve((size_t)E_EDGES * 4);           // 6.4 MB
    unsigned long long* ebuf = (unsigned long long*)carve((size_t)E_EDGES * 8);  // 12.8 MB
    _Float16* g       = (_Float16*)carve((size_t)N_NODES * F * 2);       // 51.2 MB
    (void)ws_size;

    // h (fp16, 51.2 MB) lives in the upper half of d_out; dead before agg2's lv writes land
    _Float16* h16 = (_Float16*)(out + LV_OFF);

    // ---- graph preprocessing: binned CSR build (shared by both aggregations) ----
    k_zero   <<<(NBUK + 255) / 256, 256, 0, stream>>>(gcnt, NBUK);
    k_wprep  <<<256, 256, 0, stream>>>(W1, Wmu, Wlv, Wt1, Wtc);
    k_binA   <<<NBLK_BIN, 256, 0, stream>>>(dst, gcnt, cbase);
    k_scan782<<<1, 1024, 0, stream>>>(gcnt, gbase);
    k_binC   <<<NBLK_BIN, 256, 0, stream>>>(src, dst, gbase, cbase, ebuf);
    k_binD   <<<NBUK, 256, 0, stream>>>(ebuf, gbase, csr_src, row_off, dis);

    // layer 1: g = fp16((x@W1)*dis) ; h = fp16(relu(dis*(g[self]+sum g[nbr]) + b1))
    k_gemm<float><<<782, 256, 0, stream>>>(x, Wt1, dis, g, N_NODES);
    k_aggregate_relu<<<N_NODES / 4, 256, 0, stream>>>(g, row_off, csr_src, dis, b1, h16);

    // layer 2 (mu|lv fused): g = fp16((h@Wtc^T)*dis) ; out = dis*(g[self]+sum g[nbr]) + b
    k_gemm<_Float16><<<782, 256, 0, stream>>>(h16, Wtc, dis, g, N_NODES);
    k_aggregate_out<<<N_NODES / 4, 256, 0, stream>>>(g, row_off, csr_src, dis, bmu, blv, out);
}